// Round 2
// baseline (539.435 us; speedup 1.0000x reference)
//
#include <hip/hip_runtime.h>

// RGCN layer, MI355X — round 2.
// r1 post-mortem: per-edge fp32 atomicAdd epilogue was the bottleneck
// (WRITE_SIZE 320 MB = atomic write-through, 258G atomics/s ceiling).
// New structure:
//   Phase A: rel-sorted GEMM -> per-edge bf16 rows PLAIN-stored at their
//            dst-sorted position (second counting sort), fragment-native
//            column permutation (idx = wc + lrow*4 + j  <->  col = wc + j*16 + lrow).
//   Phase B: segmented sum over dst-sorted rows, one store per dst row,
//            atomics only at wave-range boundaries.
// Chunked by ws_size (C in {1..16}): t_buf = E/C rows; tiles split at chunk
// boundaries so each tile lives in exactly one chunk.

#define N_NODES 20000
#define E_EDGES 640000
#define R_REL   65
#define TM      128
#define MAX_TILES 5120

typedef __attribute__((ext_vector_type(8))) short bf16x8;
typedef __attribute__((ext_vector_type(4))) float f32x4;

__device__ __forceinline__ unsigned short f2bf(float x) {
    union { float f; unsigned int u; } c; c.f = x;
    unsigned int b = c.u + 0x7fffu + ((c.u >> 16) & 1u);   // RTNE
    return (unsigned short)(b >> 16);
}
__device__ __forceinline__ float bf2f(unsigned short h) {
    union { unsigned int u; float f; } c; c.u = ((unsigned int)h) << 16;
    return c.f;
}

// ---------------- K0a: W32[r, i*128+o] = sum_b comp[r,b]*basis[b,i,o] ------
__global__ void k_basis_gemm(const float* __restrict__ comp,
                             const float* __restrict__ basis,
                             float* __restrict__ W32) {
    __shared__ float lc[16 * 65];
    int r0 = blockIdx.y * 16;
    int col = blockIdx.x * 256 + threadIdx.x;
    for (int j = threadIdx.x; j < 16 * 65; j += 256) {
        int rr = r0 + j / 65;
        lc[j] = (rr < R_REL) ? comp[rr * 65 + (j % 65)] : 0.f;
    }
    __syncthreads();
    float acc[16];
#pragma unroll
    for (int j = 0; j < 16; ++j) acc[j] = 0.f;
    for (int k = 0; k < 65; ++k) {
        float v = basis[k * 16384 + col];
#pragma unroll
        for (int j = 0; j < 16; ++j) acc[j] += lc[j * 65 + k] * v;
    }
#pragma unroll
    for (int j = 0; j < 16; ++j) {
        int rr = r0 + j;
        if (rr < R_REL) W32[rr * 16384 + col] = acc[j];
    }
}

// ---------------- K0b: transpose fp32 [i][o] -> bf16 [o][i] ----------------
__global__ void k_transpose_bf16(const float* __restrict__ src,
                                 unsigned short* __restrict__ dst) {
    __shared__ float tile[64][65];
    int b = blockIdx.x;
    int mat = b >> 2, ot = (b >> 1) & 1, itl = b & 1;
    const float* s = src + (size_t)mat * 16384;
    unsigned short* d = dst + (size_t)mat * 16384;
    int tx = threadIdx.x & 63, ty = threadIdx.x >> 6;
    for (int it = 0; it < 16; ++it) {
        int i = ty + it * 4;
        tile[i][tx] = s[(itl * 64 + i) * 128 + ot * 64 + tx];
    }
    __syncthreads();
    for (int it = 0; it < 16; ++it) {
        int o = ty + it * 4;
        d[(ot * 64 + o) * 128 + itl * 64 + tx] = f2bf(tile[tx][o]);
    }
}

// ---------------- K0c: node feats fp32 -> bf16 -----------------------------
__global__ void k_f32_to_bf16(const float* __restrict__ x,
                              unsigned short* __restrict__ y, int n4) {
    int i = blockIdx.x * 256 + threadIdx.x;
    if (i >= n4) return;
    float4 v = reinterpret_cast<const float4*>(x)[i];
    ushort4 o;
    o.x = f2bf(v.x); o.y = f2bf(v.y); o.z = f2bf(v.z); o.w = f2bf(v.w);
    reinterpret_cast<ushort4*>(y)[i] = o;
}

// ---------------- K1a: relation histogram ----------------------------------
__global__ void k_hist(const int* __restrict__ et, int* __restrict__ ghist) {
    __shared__ int lh[R_REL];
    if (threadIdx.x < R_REL) lh[threadIdx.x] = 0;
    __syncthreads();
    for (int i = blockIdx.x * 256 + threadIdx.x; i < E_EDGES; i += gridDim.x * 256)
        atomicAdd(&lh[et[i]], 1);
    __syncthreads();
    if (threadIdx.x < R_REL) atomicAdd(&ghist[threadIdx.x], lh[threadIdx.x]);
}

// ---------------- K1b: scan + tile descriptors (split at chunk bounds) -----
__global__ void k_scan_tiles(const int* __restrict__ ghist, int* __restrict__ cnt,
                             int* __restrict__ ntiles_p, int* __restrict__ tile_rel,
                             int* __restrict__ tile_start, int* __restrict__ tile_len,
                             int CH) {
    __shared__ int base[R_REL + 1], tb[R_REL + 1], tcnt[R_REL];
    int tid = threadIdx.x;
    if (tid == 0) {
        int b = 0;
        for (int r = 0; r < R_REL; ++r) {
            base[r] = b; b += ghist[r];
            cnt[r] = base[r];
        }
        base[R_REL] = b;
    }
    __syncthreads();
    if (tid < R_REL) {
        int s = base[tid], e = base[tid + 1], c = 0;
        while (s < e) {
            int tochunk = CH - (s - (s / CH) * CH);
            int len = min(min(TM, e - s), tochunk);
            s += len; ++c;
        }
        tcnt[tid] = c;
    }
    __syncthreads();
    if (tid == 0) {
        int t = 0;
        for (int r = 0; r < R_REL; ++r) { tb[r] = t; t += tcnt[r]; }
        tb[R_REL] = t;
        *ntiles_p = t;
    }
    __syncthreads();
    if (tid < R_REL) {
        int s = base[tid], e = base[tid + 1], j = tb[tid];
        while (s < e) {
            int tochunk = CH - (s - (s / CH) * CH);
            int len = min(min(TM, e - s), tochunk);
            tile_rel[j] = tid; tile_start[j] = s; tile_len[j] = len;
            ++j; s += len;
        }
    }
}

// ---------------- K1c: scatter edge ids into relation buckets --------------
#define SCAT_CH 2560
__global__ void k_scatter(const int* __restrict__ et, int* __restrict__ cnt,
                          int* __restrict__ perm) {
    __shared__ int lh[R_REL], lbase[R_REL];
    int c0 = blockIdx.x * SCAT_CH;
    int cend = min(c0 + SCAT_CH, E_EDGES);
    if (threadIdx.x < R_REL) lh[threadIdx.x] = 0;
    __syncthreads();
    for (int i = c0 + threadIdx.x; i < cend; i += 256) atomicAdd(&lh[et[i]], 1);
    __syncthreads();
    if (threadIdx.x < R_REL && lh[threadIdx.x] > 0)
        lbase[threadIdx.x] = atomicAdd(&cnt[threadIdx.x], lh[threadIdx.x]);
    __syncthreads();
    if (threadIdx.x < R_REL) lh[threadIdx.x] = 0;
    __syncthreads();
    for (int i = c0 + threadIdx.x; i < cend; i += 256) {
        int r = et[i];
        int p = lbase[r] + atomicAdd(&lh[r], 1);
        perm[p] = i;
    }
}

// ---------------- K1d/e/f: dst counting sort (per chunk) -------------------
__global__ void k_hist_dst(const int* __restrict__ perm, const int* __restrict__ dstA,
                           int lo, int n, int* __restrict__ gh) {
    for (int i = blockIdx.x * 256 + threadIdx.x; i < n; i += gridDim.x * 256)
        atomicAdd(&gh[dstA[perm[lo + i]]], 1);
}

__global__ void k_scan_dst(const int* __restrict__ gh, int* __restrict__ cnt) {
    __shared__ int part[1024];
    int tid = threadIdx.x;
    const int per = (N_NODES + 1023) / 1024;
    int i0 = tid * per;
    int s = 0;
    for (int k = 0; k < per; ++k) { int i = i0 + k; if (i < N_NODES) s += gh[i]; }
    part[tid] = s;
    __syncthreads();
    for (int off = 1; off < 1024; off <<= 1) {
        int v = (tid >= off) ? part[tid - off] : 0;
        __syncthreads();
        part[tid] += v;
        __syncthreads();
    }
    int b = part[tid] - s;
    for (int k = 0; k < per; ++k) {
        int i = i0 + k;
        if (i < N_NODES) { cnt[i] = b; b += gh[i]; }
    }
}

__global__ void k_scatter_dst(const int* __restrict__ perm, const int* __restrict__ dstA,
                              int lo, int n, int* __restrict__ cnt,
                              int* __restrict__ inv2, int* __restrict__ dst_sorted) {
    for (int i = blockIdx.x * 256 + threadIdx.x; i < n; i += gridDim.x * 256) {
        int e = perm[lo + i];
        int d = dstA[e];
        int p2 = atomicAdd(&cnt[d], 1);
        inv2[lo + i] = p2;
        dst_sorted[p2] = d;
    }
}

// ---------------- K2: per-relation edge GEMM -> bf16 rows at dst-pos -------
__global__ __launch_bounds__(256, 2) void k_conv_gemm(
    const int* __restrict__ tile_rel, const int* __restrict__ tile_start,
    const int* __restrict__ tile_len, const int* __restrict__ ntiles_p,
    const int* __restrict__ perm, const int* __restrict__ srcA,
    const float* __restrict__ norm, const unsigned short* __restrict__ node_bf,
    const unsigned short* __restrict__ Wt, const int* __restrict__ inv2,
    unsigned short* __restrict__ t_out, int lo, int hi) {
    __shared__ unsigned short Alds[128 * 128];
    __shared__ unsigned short Blds[128 * 128];
    __shared__ int sp2[128];
    int tid = blockIdx.x;
    if (tid >= *ntiles_p) return;
    int start = tile_start[tid];
    if (start < lo || start >= hi) return;
    int r = tile_rel[tid], len = tile_len[tid];
    int t = threadIdx.x;
    const unsigned short* Wr = Wt + (size_t)r * 16384;
#pragma unroll
    for (int it = 0; it < 8; ++it) {               // stage W (Wt[o][i] row-major)
        int j = t + 256 * it;
        int o = j >> 4, c = j & 15;
        int cs = c ^ (o & 15);
        *reinterpret_cast<uint4*>(&Blds[o * 128 + cs * 8]) =
            *reinterpret_cast<const uint4*>(Wr + o * 128 + c * 8);
    }
#pragma unroll
    for (int it = 0; it < 8; ++it) {               // stage A (norm-scaled messages)
        int j = t + 256 * it;
        int p = j >> 4, c = j & 15;
        int cs = c ^ (p & 15);
        uint4 v = {0u, 0u, 0u, 0u};
        if (p < len) {
            int e = perm[start + p];
            if (c == 0) sp2[p] = inv2[start + p];
            float nrm = norm[e];
            int s = srcA[e];
            uint4 x = *reinterpret_cast<const uint4*>(node_bf + (size_t)s * 128 + c * 8);
            const unsigned short* xs = reinterpret_cast<const unsigned short*>(&x);
            unsigned short tmp[8];
#pragma unroll
            for (int q = 0; q < 8; ++q) tmp[q] = f2bf(bf2f(xs[q]) * nrm);
            v = *reinterpret_cast<uint4*>(tmp);
        } else if (c == 0) {
            sp2[p] = 0;
        }
        *reinterpret_cast<uint4*>(&Alds[p * 128 + cs * 8]) = v;
    }
    __syncthreads();

    int w = t >> 6, lane = t & 63;
    int wr = (w >> 1) * 64, wc = (w & 1) * 64;
    int lrow = lane & 15, quad = lane >> 4;
    f32x4 acc[4][4];
#pragma unroll
    for (int i = 0; i < 4; ++i)
#pragma unroll
        for (int j = 0; j < 4; ++j) acc[i][j] = (f32x4){0.f, 0.f, 0.f, 0.f};

#pragma unroll
    for (int ks = 0; ks < 4; ++ks) {
        int cbase = ks * 4 + quad;
        bf16x8 af[4], bfr[4];
#pragma unroll
        for (int i = 0; i < 4; ++i) {
            int row = wr + i * 16 + lrow;
            int cs = cbase ^ (row & 15);
            af[i] = *reinterpret_cast<const bf16x8*>(&Alds[row * 128 + cs * 8]);
        }
#pragma unroll
        for (int j = 0; j < 4; ++j) {
            int row = wc + j * 16 + lrow;
            int cs = cbase ^ (row & 15);
            bfr[j] = *reinterpret_cast<const bf16x8*>(&Blds[row * 128 + cs * 8]);
        }
#pragma unroll
        for (int i = 0; i < 4; ++i)
#pragma unroll
            for (int j = 0; j < 4; ++j)
                acc[i][j] = __builtin_amdgcn_mfma_f32_16x16x32_bf16(af[i], bfr[j], acc[i][j], 0, 0, 0);
    }

    // epilogue: row m, permuted layout: pos (wc + lrow*4 + j) <-> col (wc + j*16 + lrow)
    // lanes of a quad fill one contiguous 128B half-row per store round.
#pragma unroll
    for (int i = 0; i < 4; ++i) {
        int m0 = wr + i * 16 + quad * 4;
#pragma unroll
        for (int reg = 0; reg < 4; ++reg) {
            int m = m0 + reg;
            if (m < len) {
                int p2 = sp2[m];
                ushort4 v;
                v.x = f2bf(acc[i][0][reg]);
                v.y = f2bf(acc[i][1][reg]);
                v.z = f2bf(acc[i][2][reg]);
                v.w = f2bf(acc[i][3][reg]);
                *reinterpret_cast<ushort4*>(t_out + (size_t)p2 * 128 + wc + lrow * 4) = v;
            }
        }
    }
}

// ---------------- K2b: segmented sum over dst-sorted bf16 rows -------------
__global__ __launch_bounds__(256) void k_reduce(const unsigned short* __restrict__ t,
                                                const int* __restrict__ dst_sorted,
                                                int n, int use_atomic,
                                                float* __restrict__ h) {
    const int L = 256;                       // edges per wave
    int w = threadIdx.x >> 6, lane = threadIdx.x & 63;
    int a = (blockIdx.x * 4 + w) * L;
    if (a >= n) return;
    int b = min(a + L, n);
    int idx0 = lane * 2, idx1 = idx0 + 1;
    int n0 = (idx0 & 64) + (idx0 & 3) * 16 + ((idx0 >> 2) & 15);
    int n1 = (idx1 & 64) + (idx1 & 3) * 16 + ((idx1 >> 2) & 15);
    float s0 = 0.f, s1 = 0.f;
    int cur = dst_sorted[a];
    bool closed_left = (a == 0) || (dst_sorted[a - 1] != cur);
    for (int q = a; q < b; ++q) {
        int d = dst_sorted[q];
        if (d != cur) {
            float* p = h + (size_t)cur * 128;
            if (closed_left && !use_atomic) { p[n0] = s0; p[n1] = s1; }
            else { atomicAdd(p + n0, s0); atomicAdd(p + n1, s1); }
            cur = d; s0 = 0.f; s1 = 0.f; closed_left = true;
        }
        unsigned int u = *reinterpret_cast<const unsigned int*>(t + (size_t)q * 128 + idx0);
        s0 += bf2f((unsigned short)(u & 0xffffu));
        s1 += bf2f((unsigned short)(u >> 16));
    }
    bool closed_right = (b == n) || (dst_sorted[b] != cur);
    float* p = h + (size_t)cur * 128;
    if (closed_left && closed_right && !use_atomic) { p[n0] = s0; p[n1] = s1; }
    else { atomicAdd(p + n0, s0); atomicAdd(p + n1, s1); }
}

// ---------------- K3: residual GEMM relu(x @ W_res + b_res) ----------------
__global__ __launch_bounds__(256, 2) void k_resid_gemm(
    const unsigned short* __restrict__ node_bf,
    const unsigned short* __restrict__ Wrest, const float* __restrict__ b_res,
    float* __restrict__ resid) {
    __shared__ unsigned short Alds[128 * 128];
    __shared__ unsigned short Blds[128 * 128];
    int row0 = blockIdx.x * 128;
    int t = threadIdx.x;
#pragma unroll
    for (int it = 0; it < 8; ++it) {
        int j = t + 256 * it;
        int o = j >> 4, c = j & 15;
        int cs = c ^ (o & 15);
        *reinterpret_cast<uint4*>(&Blds[o * 128 + cs * 8]) =
            *reinterpret_cast<const uint4*>(Wrest + o * 128 + c * 8);
    }
#pragma unroll
    for (int it = 0; it < 8; ++it) {
        int j = t + 256 * it;
        int p = j >> 4, c = j & 15;
        int cs = c ^ (p & 15);
        uint4 v = {0u, 0u, 0u, 0u};
        int row = row0 + p;
        if (row < N_NODES)
            v = *reinterpret_cast<const uint4*>(node_bf + (size_t)row * 128 + c * 8);
        *reinterpret_cast<uint4*>(&Alds[p * 128 + cs * 8]) = v;
    }
    __syncthreads();

    int w = t >> 6, lane = t & 63;
    int wr = (w >> 1) * 64, wc = (w & 1) * 64;
    int lrow = lane & 15, quad = lane >> 4;
    f32x4 acc[4][4];
#pragma unroll
    for (int i = 0; i < 4; ++i)
#pragma unroll
        for (int j = 0; j < 4; ++j) acc[i][j] = (f32x4){0.f, 0.f, 0.f, 0.f};
#pragma unroll
    for (int ks = 0; ks < 4; ++ks) {
        int cbase = ks * 4 + quad;
        bf16x8 af[4], bfr[4];
#pragma unroll
        for (int i = 0; i < 4; ++i) {
            int row = wr + i * 16 + lrow;
            int cs = cbase ^ (row & 15);
            af[i] = *reinterpret_cast<const bf16x8*>(&Alds[row * 128 + cs * 8]);
        }
#pragma unroll
        for (int j = 0; j < 4; ++j) {
            int row = wc + j * 16 + lrow;
            int cs = cbase ^ (row & 15);
            bfr[j] = *reinterpret_cast<const bf16x8*>(&Blds[row * 128 + cs * 8]);
        }
#pragma unroll
        for (int i = 0; i < 4; ++i)
#pragma unroll
            for (int j = 0; j < 4; ++j)
                acc[i][j] = __builtin_amdgcn_mfma_f32_16x16x32_bf16(af[i], bfr[j], acc[i][j], 0, 0, 0);
    }
#pragma unroll
    for (int i = 0; i < 4; ++i) {
        int m0 = wr + i * 16 + quad * 4;
#pragma unroll
        for (int reg = 0; reg < 4; ++reg) {
            int grow = row0 + m0 + reg;
            if (grow < N_NODES) {
#pragma unroll
                for (int j = 0; j < 4; ++j) {
                    int n = wc + j * 16 + lrow;
                    float v = acc[i][j][reg] + b_res[n];
                    resid[(size_t)grow * 128 + n] = fmaxf(v, 0.f);
                }
            }
        }
    }
}

// ---------------- K4: h = relu(conv+bias)+resid, col sums ------------------
__global__ void k_combine_stats(float* __restrict__ h, const float* __restrict__ resid,
                                const float* __restrict__ h_bias,
                                float* __restrict__ colsum, float* __restrict__ colsumsq) {
    int col = threadIdx.x & 127, half = threadIdx.x >> 7;
    int row0 = blockIdx.x * 64;
    float bias = h_bias[col];
    float s1 = 0.f, s2 = 0.f;
    for (int it = 0; it < 32; ++it) {
        int row = row0 + half * 32 + it;
        if (row < N_NODES) {
            size_t idx = (size_t)row * 128 + col;
            float v = fmaxf(h[idx] + bias, 0.f) + resid[idx];
            h[idx] = v;
            s1 += v; s2 += v * v;
        }
    }
    __shared__ float ls1[256], ls2[256];
    ls1[threadIdx.x] = s1; ls2[threadIdx.x] = s2;
    __syncthreads();
    if (threadIdx.x < 128) {
        atomicAdd(&colsum[threadIdx.x], ls1[threadIdx.x] + ls1[threadIdx.x + 128]);
        atomicAdd(&colsumsq[threadIdx.x], ls2[threadIdx.x] + ls2[threadIdx.x + 128]);
    }
}

// ---------------- K5: BN apply ---------------------------------------------
__global__ void k_bn(float* __restrict__ h, const float* __restrict__ colsum,
                     const float* __restrict__ colsumsq, const float* __restrict__ gamma,
                     const float* __restrict__ beta) {
    __shared__ float sc[128], sh[128];
    if (threadIdx.x < 128) {
        float m = colsum[threadIdx.x] * (1.f / N_NODES);
        float var = colsumsq[threadIdx.x] * (1.f / N_NODES) - m * m;
        float s = gamma[threadIdx.x] * rsqrtf(var + 1e-5f);
        sc[threadIdx.x] = s;
        sh[threadIdx.x] = beta[threadIdx.x] - m * s;
    }
    __syncthreads();
    const int total4 = N_NODES * 32;
    for (int i = blockIdx.x * 256 + threadIdx.x; i < total4; i += gridDim.x * 256) {
        float4 v = reinterpret_cast<float4*>(h)[i];
        int c = (i * 4) & 127;
        v.x = v.x * sc[c] + sh[c];
        v.y = v.y * sc[c + 1] + sh[c + 1];
        v.z = v.z * sc[c + 2] + sh[c + 2];
        v.w = v.w * sc[c + 3] + sh[c + 3];
        reinterpret_cast<float4*>(h)[i] = v;
    }
}

extern "C" void kernel_launch(void* const* d_in, const int* in_sizes, int n_in,
                              void* d_out, int out_size, void* d_ws, size_t ws_size,
                              hipStream_t stream) {
    (void)in_sizes; (void)n_in; (void)out_size;
    const float* node_feats = (const float*)d_in[0];
    const int* src    = (const int*)d_in[1];
    const int* dst    = (const int*)d_in[2];
    const int* etype  = (const int*)d_in[3];
    const float* norm = (const float*)d_in[4];
    const float* basis = (const float*)d_in[5];
    const float* comp  = (const float*)d_in[6];
    const float* h_bias = (const float*)d_in[7];
    const float* W_res  = (const float*)d_in[8];
    const float* b_res  = (const float*)d_in[9];
    const float* gamma  = (const float*)d_in[10];
    const float* beta   = (const float*)d_in[11];

    char* ws = (char*)d_ws;
    int* ghist      = (int*)(ws + 0);
    int* cnt        = (int*)(ws + 1024);
    int* ntiles_p   = (int*)(ws + 2048);
    float* colsum   = (float*)(ws + 2560);
    float* colsumsq = (float*)(ws + 3072);
    int* tile_rel   = (int*)(ws + 8192);
    int* tile_start = (int*)(ws + 28672);
    int* tile_len   = (int*)(ws + 49152);
    int* ghist_dst  = (int*)(ws + 69632);
    int* cnt_dst    = (int*)(ws + 151552);
    float* W32      = (float*)(ws + 233472);
    unsigned short* Wt      = (unsigned short*)(ws + 4493312);
    unsigned short* Wrest   = (unsigned short*)(ws + 6623232);
    unsigned short* node_bf = (unsigned short*)(ws + 6656000);
    int* perm       = (int*)(ws + 11776000);
    int* inv2       = (int*)(ws + 14336000);
    float* resid    = (float*)(ws + 16896000);
    // chunk-sized buffers at the end
    const long BASE_END = 27136000L;

    // pick chunk count from ws_size (deterministic -> graph-capture safe)
    int C = 1;
    while (C < 16) {
        long ch = E_EDGES / C;
        if (BASE_END + ch * 4L + ch * 256L <= (long)ws_size) break;
        C <<= 1;
    }
    int CH = E_EDGES / C;
    int* dst_sorted = (int*)(ws + BASE_END);
    unsigned short* t_buf = (unsigned short*)(ws + BASE_END + (long)CH * 4L);
    float* hacc = (float*)d_out;

    hipMemsetAsync(ws, 0, 8192, stream);
    hipMemsetAsync(d_out, 0, (size_t)N_NODES * 128 * 4, stream);

    k_basis_gemm<<<dim3(64, 5), 256, 0, stream>>>(comp, basis, W32);
    k_transpose_bf16<<<R_REL * 4, 256, 0, stream>>>(W32, Wt);
    k_transpose_bf16<<<4, 256, 0, stream>>>(W_res, Wrest);
    k_f32_to_bf16<<<2500, 256, 0, stream>>>(node_feats, node_bf, N_NODES * 32);
    k_hist<<<256, 256, 0, stream>>>(etype, ghist);
    k_scan_tiles<<<1, 256, 0, stream>>>(ghist, cnt, ntiles_p, tile_rel, tile_start, tile_len, CH);
    k_scatter<<<(E_EDGES + SCAT_CH - 1) / SCAT_CH, 256, 0, stream>>>(etype, cnt, perm);
    k_resid_gemm<<<(N_NODES + 127) / 128, 256, 0, stream>>>(node_bf, Wrest, b_res, resid);

    for (int c = 0; c < C; ++c) {
        int lo = c * CH, hi = lo + CH;
        hipMemsetAsync(ghist_dst, 0, 81920, stream);
        k_hist_dst<<<256, 256, 0, stream>>>(perm, dst, lo, CH, ghist_dst);
        k_scan_dst<<<1, 1024, 0, stream>>>(ghist_dst, cnt_dst);
        k_scatter_dst<<<256, 256, 0, stream>>>(perm, dst, lo, CH, cnt_dst, inv2, dst_sorted);
        k_conv_gemm<<<MAX_TILES, 256, 0, stream>>>(tile_rel, tile_start, tile_len, ntiles_p,
                                                   perm, src, norm, node_bf, Wt, inv2,
                                                   t_buf, lo, hi);
        k_reduce<<<(CH + 1023) / 1024, 256, 0, stream>>>(t_buf, dst_sorted, CH,
                                                         (C > 1) ? 1 : 0, hacc);
    }

    k_combine_stats<<<(N_NODES + 63) / 64, 256, 0, stream>>>(hacc, resid, h_bias, colsum, colsumsq);
    k_bn<<<512, 256, 0, stream>>>(hacc, colsum, colsumsq, gamma, beta);
}

// Round 3
// 387.950 us; speedup vs baseline: 1.3905x; 1.3905x over previous
//
#include <hip/hip_runtime.h>
#include <hip/hip_bf16.h>

// RGCN layer, MI355X — round 3.
// r2 post-mortem: k_reduce latency-bound (713 GB/s, 1 dword load in flight);
// per-chunk dst-sort pipeline overhead. Fixes:
//  - k_reduce: CSR (seg_ptr per chunk), 16-lane group per dst, uint4 loads,
//    4-deep unroll, plain stores (RMW accumulate for chunk>0; no atomics).
//  - dst-sort hoisted out of chunk loop: one hist over [chunk][dst], parallel
//    3-kernel scan, one scatter. Chunk loop = conv + reduce only.
//  - conv: norm folded into epilogue (gather is pure copy), A/B staged via
//    global_load_lds width 16 (XOR swizzle applied to SOURCE chunk so LDS
//    dest is lane-linear), packed bf16 cvt in epilogue.
//  - columns stay in MFMA-permuted order through h/resid/stats; k_bn
//    unpermutes via LDS tile on the final store.

#define N_NODES 20000
#define E_EDGES 640000
#define R_REL   65
#define TM      128
#define MAX_TILES 5120
#define SEGSTRIDE 20001

typedef __attribute__((ext_vector_type(8))) short bf16x8;
typedef __attribute__((ext_vector_type(4))) float f32x4;

__device__ __forceinline__ unsigned short f2bf(float x) {
    union { float f; unsigned int u; } c; c.f = x;
    unsigned int b = c.u + 0x7fffu + ((c.u >> 16) & 1u);   // RTNE
    return (unsigned short)(b >> 16);
}
__device__ __forceinline__ float bf2f_lo(unsigned int u) {
    union { unsigned int u; float f; } c; c.u = u << 16; return c.f;
}
__device__ __forceinline__ float bf2f_hi(unsigned int u) {
    union { unsigned int u; float f; } c; c.u = u & 0xffff0000u; return c.f;
}
__device__ __forceinline__ void async16(const void* g, void* l) {
    __builtin_amdgcn_global_load_lds(
        (const __attribute__((address_space(1))) unsigned int*)g,
        (__attribute__((address_space(3))) unsigned int*)l, 16, 0, 0);
}
// permuted pos -> true col
__device__ __forceinline__ int unperm(int p) {
    return (p & 64) + ((p & 3) << 4) + ((p >> 2) & 15);
}

// ---------------- K0a: W32[r, i*128+o] = sum_b comp[r,b]*basis[b,i,o] ------
__global__ void k_basis_gemm(const float* __restrict__ comp,
                             const float* __restrict__ basis,
                             float* __restrict__ W32) {
    __shared__ float lc[16 * 65];
    int r0 = blockIdx.y * 16;
    int col = blockIdx.x * 256 + threadIdx.x;
    for (int j = threadIdx.x; j < 16 * 65; j += 256) {
        int rr = r0 + j / 65;
        lc[j] = (rr < R_REL) ? comp[rr * 65 + (j % 65)] : 0.f;
    }
    __syncthreads();
    float acc[16];
#pragma unroll
    for (int j = 0; j < 16; ++j) acc[j] = 0.f;
    for (int k = 0; k < 65; ++k) {
        float v = basis[k * 16384 + col];
#pragma unroll
        for (int j = 0; j < 16; ++j) acc[j] += lc[j * 65 + k] * v;
    }
#pragma unroll
    for (int j = 0; j < 16; ++j) {
        int rr = r0 + j;
        if (rr < R_REL) W32[rr * 16384 + col] = acc[j];
    }
}

// ---------------- K0b: transpose fp32 [i][o] -> bf16 [o][i] ----------------
__global__ void k_transpose_bf16(const float* __restrict__ src,
                                 unsigned short* __restrict__ dst) {
    __shared__ float tile[64][65];
    int b = blockIdx.x;
    int mat = b >> 2, ot = (b >> 1) & 1, itl = b & 1;
    const float* s = src + (size_t)mat * 16384;
    unsigned short* d = dst + (size_t)mat * 16384;
    int tx = threadIdx.x & 63, ty = threadIdx.x >> 6;
    for (int it = 0; it < 16; ++it) {
        int i = ty + it * 4;
        tile[i][tx] = s[(itl * 64 + i) * 128 + ot * 64 + tx];
    }
    __syncthreads();
    for (int it = 0; it < 16; ++it) {
        int o = ty + it * 4;
        d[(ot * 64 + o) * 128 + itl * 64 + tx] = f2bf(tile[tx][o]);
    }
}

// ---------------- K0c: node feats fp32 -> bf16 -----------------------------
__global__ void k_f32_to_bf16(const float* __restrict__ x,
                              unsigned short* __restrict__ y, int n4) {
    int i = blockIdx.x * 256 + threadIdx.x;
    if (i >= n4) return;
    float4 v = reinterpret_cast<const float4*>(x)[i];
    ushort4 o;
    o.x = f2bf(v.x); o.y = f2bf(v.y); o.z = f2bf(v.z); o.w = f2bf(v.w);
    reinterpret_cast<ushort4*>(y)[i] = o;
}

// ---------------- K1a: relation histogram ----------------------------------
__global__ void k_hist(const int* __restrict__ et, int* __restrict__ ghist) {
    __shared__ int lh[R_REL];
    if (threadIdx.x < R_REL) lh[threadIdx.x] = 0;
    __syncthreads();
    for (int i = blockIdx.x * 256 + threadIdx.x; i < E_EDGES; i += gridDim.x * 256)
        atomicAdd(&lh[et[i]], 1);
    __syncthreads();
    if (threadIdx.x < R_REL) atomicAdd(&ghist[threadIdx.x], lh[threadIdx.x]);
}

// ---------------- K1b: scan + tile descriptors (split at chunk bounds) -----
__global__ void k_scan_tiles(const int* __restrict__ ghist, int* __restrict__ cnt,
                             int* __restrict__ ntiles_p, int* __restrict__ tile_rel,
                             int* __restrict__ tile_start, int* __restrict__ tile_len,
                             int CH) {
    __shared__ int base[R_REL + 1], tb[R_REL + 1], tcnt[R_REL];
    int tid = threadIdx.x;
    if (tid == 0) {
        int b = 0;
        for (int r = 0; r < R_REL; ++r) {
            base[r] = b; b += ghist[r];
            cnt[r] = base[r];
        }
        base[R_REL] = b;
    }
    __syncthreads();
    if (tid < R_REL) {
        int s = base[tid], e = base[tid + 1], c = 0;
        while (s < e) {
            int tochunk = CH - (s - (s / CH) * CH);
            int len = min(min(TM, e - s), tochunk);
            s += len; ++c;
        }
        tcnt[tid] = c;
    }
    __syncthreads();
    if (tid == 0) {
        int t = 0;
        for (int r = 0; r < R_REL; ++r) { tb[r] = t; t += tcnt[r]; }
        tb[R_REL] = t;
        *ntiles_p = t;
    }
    __syncthreads();
    if (tid < R_REL) {
        int s = base[tid], e = base[tid + 1], j = tb[tid];
        while (s < e) {
            int tochunk = CH - (s - (s / CH) * CH);
            int len = min(min(TM, e - s), tochunk);
            tile_rel[j] = tid; tile_start[j] = s; tile_len[j] = len;
            ++j; s += len;
        }
    }
}

// ---------------- K1c: scatter edge ids into relation buckets --------------
#define SCAT_CH 2560
__global__ void k_scatter(const int* __restrict__ et, int* __restrict__ cnt,
                          int* __restrict__ perm) {
    __shared__ int lh[R_REL], lbase[R_REL];
    int c0 = blockIdx.x * SCAT_CH;
    int cend = min(c0 + SCAT_CH, E_EDGES);
    if (threadIdx.x < R_REL) lh[threadIdx.x] = 0;
    __syncthreads();
    for (int i = c0 + threadIdx.x; i < cend; i += 256) atomicAdd(&lh[et[i]], 1);
    __syncthreads();
    if (threadIdx.x < R_REL && lh[threadIdx.x] > 0)
        lbase[threadIdx.x] = atomicAdd(&cnt[threadIdx.x], lh[threadIdx.x]);
    __syncthreads();
    if (threadIdx.x < R_REL) lh[threadIdx.x] = 0;
    __syncthreads();
    for (int i = c0 + threadIdx.x; i < cend; i += 256) {
        int r = et[i];
        int p = lbase[r] + atomicAdd(&lh[r], 1);
        perm[p] = i;
    }
}

// ---------------- K1d: dst histogram, all chunks at once -------------------
__global__ void k_hist_dst_all(const int* __restrict__ perm, const int* __restrict__ dstA,
                               int CH, int* __restrict__ gh2) {
    for (int i = blockIdx.x * 256 + threadIdx.x; i < E_EDGES; i += gridDim.x * 256) {
        int c = i / CH;
        atomicAdd(&gh2[c * N_NODES + dstA[perm[i]]], 1);
    }
}

// ---------------- K1e: 3-phase parallel scan per chunk ---------------------
__global__ void k_scanA(const int* __restrict__ gh2, int* __restrict__ bsum) {
    int c = blockIdx.x / 80, jb = blockIdx.x % 80;
    int i = jb * 256 + threadIdx.x;
    int v = (i < N_NODES) ? gh2[c * N_NODES + i] : 0;
    __shared__ int red[256];
    red[threadIdx.x] = v;
    __syncthreads();
    for (int off = 128; off > 0; off >>= 1) {
        if (threadIdx.x < off) red[threadIdx.x] += red[threadIdx.x + off];
        __syncthreads();
    }
    if (threadIdx.x == 0) bsum[c * 80 + jb] = red[0];
}

__global__ void k_scanB(int* __restrict__ bsum, int nchunks) {
    int w = threadIdx.x >> 6, l = threadIdx.x & 63;
    for (int c = w; c < nchunks; c += 4) {
        int* b = bsum + c * 80;
        int v0 = b[l];
        int x = v0;
#pragma unroll
        for (int off = 1; off < 64; off <<= 1) {
            int y = __shfl_up(x, off);
            if (l >= off) x += y;
        }
        int tot0 = __shfl(x, 63);
        int v1 = (l < 16) ? b[64 + l] : 0;
        int x1 = v1;
#pragma unroll
        for (int off = 1; off < 16; off <<= 1) {
            int y = __shfl_up(x1, off);
            if (l >= off) x1 += y;
        }
        b[l] = x - v0;                       // exclusive
        if (l < 16) b[64 + l] = (x1 - v1) + tot0;
    }
}

__global__ void k_scanC(const int* __restrict__ gh2, const int* __restrict__ bsum,
                        int* __restrict__ cnt2, int* __restrict__ seg2, int CH) {
    int c = blockIdx.x / 80, jb = blockIdx.x % 80;
    int i = jb * 256 + threadIdx.x;
    int v = (i < N_NODES) ? gh2[c * N_NODES + i] : 0;
    __shared__ int red[256];
    red[threadIdx.x] = v;
    __syncthreads();
    for (int off = 1; off < 256; off <<= 1) {
        int x = (threadIdx.x >= off) ? red[threadIdx.x - off] : 0;
        __syncthreads();
        red[threadIdx.x] += x;
        __syncthreads();
    }
    int excl = red[threadIdx.x] - v + bsum[c * 80 + jb];
    if (i < N_NODES) {
        cnt2[c * N_NODES + i] = excl;
        seg2[c * SEGSTRIDE + i] = excl;
        if (i == N_NODES - 1) seg2[c * SEGSTRIDE + N_NODES] = excl + v;   // == CH
    }
}

// ---------------- K1f: scatter -> inv2 (position within chunk) -------------
__global__ void k_scatter_dst_all(const int* __restrict__ perm, const int* __restrict__ dstA,
                                  int CH, int* __restrict__ cnt2, int* __restrict__ inv2) {
    for (int i = blockIdx.x * 256 + threadIdx.x; i < E_EDGES; i += gridDim.x * 256) {
        int c = i / CH;
        int d = dstA[perm[i]];
        inv2[i] = atomicAdd(&cnt2[c * N_NODES + d], 1);
    }
}

// ---------------- K2: per-relation edge GEMM -> bf16 rows at dst-pos -------
__global__ __launch_bounds__(256, 2) void k_conv_gemm(
    const int* __restrict__ tile_rel, const int* __restrict__ tile_start,
    const int* __restrict__ tile_len, const int* __restrict__ ntiles_p,
    const int* __restrict__ perm, const int* __restrict__ srcA,
    const float* __restrict__ norm, const unsigned short* __restrict__ node_bf,
    const unsigned short* __restrict__ Wt, const int* __restrict__ inv2,
    unsigned short* __restrict__ t_out, int lo, int hi) {
    __shared__ unsigned short Alds[128 * 128];
    __shared__ unsigned short Blds[128 * 128];
    __shared__ float snorm[128];
    __shared__ int sp2[128];
    int tid = blockIdx.x;
    if (tid >= *ntiles_p) return;
    int start = tile_start[tid];
    if (start < lo || start >= hi) return;
    int r = tile_rel[tid], len = tile_len[tid];
    int t = threadIdx.x;
    const unsigned short* Wr = Wt + (size_t)r * 16384;
#pragma unroll
    for (int it = 0; it < 8; ++it) {               // stage W: XOR on SOURCE chunk
        int j = t + 256 * it;
        int o = j >> 4, c = j & 15, cs = c ^ (o & 15);
        async16(Wr + o * 128 + cs * 8, &Blds[o * 128 + c * 8]);
    }
#pragma unroll
    for (int it = 0; it < 8; ++it) {               // stage A: pure gather, no scaling
        int j = t + 256 * it;
        int p = j >> 4, c = j & 15, cs = c ^ (p & 15);
        if (p < len) {
            int e = perm[start + p];
            int s = srcA[e];
            async16(node_bf + (size_t)s * 128 + cs * 8, &Alds[p * 128 + c * 8]);
        }
    }
    if (t < len) {
        int e = perm[start + t];
        snorm[t] = norm[e];
        sp2[t] = inv2[start + t];
    }
    __syncthreads();

    int w = t >> 6, lane = t & 63;
    int wr = (w >> 1) * 64, wc = (w & 1) * 64;
    int lrow = lane & 15, quad = lane >> 4;
    f32x4 acc[4][4];
#pragma unroll
    for (int i = 0; i < 4; ++i)
#pragma unroll
        for (int j = 0; j < 4; ++j) acc[i][j] = (f32x4){0.f, 0.f, 0.f, 0.f};

#pragma unroll
    for (int ks = 0; ks < 4; ++ks) {
        int cbase = ks * 4 + quad;
        bf16x8 af[4], bfr[4];
#pragma unroll
        for (int i = 0; i < 4; ++i) {
            int row = wr + i * 16 + lrow;
            int cs = cbase ^ (row & 15);
            af[i] = *reinterpret_cast<const bf16x8*>(&Alds[row * 128 + cs * 8]);
        }
#pragma unroll
        for (int j = 0; j < 4; ++j) {
            int row = wc + j * 16 + lrow;
            int cs = cbase ^ (row & 15);
            bfr[j] = *reinterpret_cast<const bf16x8*>(&Blds[row * 128 + cs * 8]);
        }
#pragma unroll
        for (int i = 0; i < 4; ++i)
#pragma unroll
            for (int j = 0; j < 4; ++j)
                acc[i][j] = __builtin_amdgcn_mfma_f32_16x16x32_bf16(af[i], bfr[j], acc[i][j], 0, 0, 0);
    }

    // epilogue: scale by norm, pack bf16, store permuted row chunk (8B/lane,
    // a quad's 16 lanes fill 128B contiguous of row p2).
#pragma unroll
    for (int i = 0; i < 4; ++i) {
        int m0 = wr + i * 16 + quad * 4;
#pragma unroll
        for (int reg = 0; reg < 4; ++reg) {
            int m = m0 + reg;
            if (m < len) {
                float nm = snorm[m];
                int p2 = sp2[m];
                float2 lo2 = make_float2(acc[i][0][reg] * nm, acc[i][1][reg] * nm);
                float2 hi2 = make_float2(acc[i][2][reg] * nm, acc[i][3][reg] * nm);
                __hip_bfloat162 blo = __float22bfloat162_rn(lo2);
                __hip_bfloat162 bhi = __float22bfloat162_rn(hi2);
                uint2 st;
                st.x = *reinterpret_cast<unsigned int*>(&blo);
                st.y = *reinterpret_cast<unsigned int*>(&bhi);
                *reinterpret_cast<uint2*>(t_out + (size_t)p2 * 128 + wc + lrow * 4) = st;
            }
        }
    }
}

// ---------------- K2b: CSR segmented sum, 16-lane group per dst ------------
__global__ __launch_bounds__(256) void k_reduce(const unsigned short* __restrict__ t,
                                                const int* __restrict__ seg,
                                                int accum, float* __restrict__ h) {
    int d = blockIdx.x * 16 + (threadIdx.x >> 4);
    if (d >= N_NODES) return;
    int c = threadIdx.x & 15;
    int a = seg[d], b = seg[d + 1];
    if (a == b) return;
    float s[8];
#pragma unroll
    for (int k = 0; k < 8; ++k) s[k] = 0.f;
    int q = a;
    for (; q + 4 <= b; q += 4) {
        uint4 v0 = *reinterpret_cast<const uint4*>(t + (size_t)(q + 0) * 128 + c * 8);
        uint4 v1 = *reinterpret_cast<const uint4*>(t + (size_t)(q + 1) * 128 + c * 8);
        uint4 v2 = *reinterpret_cast<const uint4*>(t + (size_t)(q + 2) * 128 + c * 8);
        uint4 v3 = *reinterpret_cast<const uint4*>(t + (size_t)(q + 3) * 128 + c * 8);
        const uint4* vs[4] = {&v0, &v1, &v2, &v3};
#pragma unroll
        for (int z = 0; z < 4; ++z) {
            const unsigned int* u = reinterpret_cast<const unsigned int*>(vs[z]);
#pragma unroll
            for (int k = 0; k < 4; ++k) {
                s[2 * k]     += bf2f_lo(u[k]);
                s[2 * k + 1] += bf2f_hi(u[k]);
            }
        }
    }
    for (; q < b; ++q) {
        uint4 v = *reinterpret_cast<const uint4*>(t + (size_t)q * 128 + c * 8);
        const unsigned int* u = reinterpret_cast<const unsigned int*>(&v);
#pragma unroll
        for (int k = 0; k < 4; ++k) {
            s[2 * k]     += bf2f_lo(u[k]);
            s[2 * k + 1] += bf2f_hi(u[k]);
        }
    }
    float* p = h + (size_t)d * 128 + c * 8;
    if (accum) {
        float4 e0 = *reinterpret_cast<float4*>(p);
        float4 e1 = *reinterpret_cast<float4*>(p + 4);
        s[0] += e0.x; s[1] += e0.y; s[2] += e0.z; s[3] += e0.w;
        s[4] += e1.x; s[5] += e1.y; s[6] += e1.z; s[7] += e1.w;
    }
    *reinterpret_cast<float4*>(p)     = make_float4(s[0], s[1], s[2], s[3]);
    *reinterpret_cast<float4*>(p + 4) = make_float4(s[4], s[5], s[6], s[7]);
}

// ---------------- K3: residual GEMM relu(x @ W_res + b_res), permuted store
__global__ __launch_bounds__(256, 2) void k_resid_gemm(
    const unsigned short* __restrict__ node_bf,
    const unsigned short* __restrict__ Wrest, const float* __restrict__ b_res,
    float* __restrict__ resid) {
    __shared__ unsigned short Alds[128 * 128];
    __shared__ unsigned short Blds[128 * 128];
    int row0 = blockIdx.x * 128;
    int t = threadIdx.x;
    int nrows = min(128, N_NODES - row0);
#pragma unroll
    for (int it = 0; it < 8; ++it) {
        int j = t + 256 * it;
        int o = j >> 4, c = j & 15, cs = c ^ (o & 15);
        async16(Wrest + o * 128 + cs * 8, &Blds[o * 128 + c * 8]);
    }
#pragma unroll
    for (int it = 0; it < 8; ++it) {
        int j = t + 256 * it;
        int p = j >> 4, c = j & 15, cs = c ^ (p & 15);
        if (p < nrows)
            async16(node_bf + (size_t)(row0 + p) * 128 + cs * 8, &Alds[p * 128 + c * 8]);
    }
    __syncthreads();

    int w = t >> 6, lane = t & 63;
    int wr = (w >> 1) * 64, wc = (w & 1) * 64;
    int lrow = lane & 15, quad = lane >> 4;
    f32x4 acc[4][4];
#pragma unroll
    for (int i = 0; i < 4; ++i)
#pragma unroll
        for (int j = 0; j < 4; ++j) acc[i][j] = (f32x4){0.f, 0.f, 0.f, 0.f};
#pragma unroll
    for (int ks = 0; ks < 4; ++ks) {
        int cbase = ks * 4 + quad;
        bf16x8 af[4], bfr[4];
#pragma unroll
        for (int i = 0; i < 4; ++i) {
            int row = wr + i * 16 + lrow;
            int cs = cbase ^ (row & 15);
            af[i] = *reinterpret_cast<const bf16x8*>(&Alds[row * 128 + cs * 8]);
        }
#pragma unroll
        for (int j = 0; j < 4; ++j) {
            int row = wc + j * 16 + lrow;
            int cs = cbase ^ (row & 15);
            bfr[j] = *reinterpret_cast<const bf16x8*>(&Blds[row * 128 + cs * 8]);
        }
#pragma unroll
        for (int i = 0; i < 4; ++i)
#pragma unroll
            for (int j = 0; j < 4; ++j)
                acc[i][j] = __builtin_amdgcn_mfma_f32_16x16x32_bf16(af[i], bfr[j], acc[i][j], 0, 0, 0);
    }
    float br0 = b_res[wc + lrow];            // j=0 true col
    float br1 = b_res[wc + 16 + lrow];
    float br2 = b_res[wc + 32 + lrow];
    float br3 = b_res[wc + 48 + lrow];
#pragma unroll
    for (int i = 0; i < 4; ++i) {
        int m0 = wr + i * 16 + quad * 4;
#pragma unroll
        for (int reg = 0; reg < 4; ++reg) {
            int grow = row0 + m0 + reg;
            if (grow < N_NODES) {
                float4 v;
                v.x = fmaxf(acc[i][0][reg] + br0, 0.f);
                v.y = fmaxf(acc[i][1][reg] + br1, 0.f);
                v.z = fmaxf(acc[i][2][reg] + br2, 0.f);
                v.w = fmaxf(acc[i][3][reg] + br3, 0.f);
                *reinterpret_cast<float4*>(resid + (size_t)grow * 128 + wc + lrow * 4) = v;
            }
        }
    }
}

// ---------------- K4: h = relu(conv+bias)+resid, col sums (permuted space) -
__global__ void k_combine_stats(float* __restrict__ h, const float* __restrict__ resid,
                                const float* __restrict__ h_bias,
                                float* __restrict__ colsum, float* __restrict__ colsumsq) {
    int p = threadIdx.x & 127, half = threadIdx.x >> 7;
    int row0 = blockIdx.x * 64;
    float bias = h_bias[unperm(p)];
    float s1 = 0.f, s2 = 0.f;
    for (int it = 0; it < 32; ++it) {
        int row = row0 + half * 32 + it;
        if (row < N_NODES) {
            size_t idx = (size_t)row * 128 + p;
            float v = fmaxf(h[idx] + bias, 0.f) + resid[idx];
            h[idx] = v;
            s1 += v; s2 += v * v;
        }
    }
    __shared__ float ls1[256], ls2[256];
    ls1[threadIdx.x] = s1; ls2[threadIdx.x] = s2;
    __syncthreads();
    if (threadIdx.x < 128) {
        atomicAdd(&colsum[threadIdx.x], ls1[threadIdx.x] + ls1[threadIdx.x + 128]);
        atomicAdd(&colsumsq[threadIdx.x], ls2[threadIdx.x] + ls2[threadIdx.x + 128]);
    }
}

// ---------------- K5: BN apply + unpermute to natural cols -----------------
__global__ void k_bn(float* __restrict__ h, const float* __restrict__ colsum,
                     const float* __restrict__ colsumsq, const float* __restrict__ gamma,
                     const float* __restrict__ beta) {
    __shared__ float sc[128], sh[128], tile[8][128];
    int t = threadIdx.x;
    if (t < 128) {
        int n = unperm(t);
        float m = colsum[t] * (1.f / N_NODES);
        float var = colsumsq[t] * (1.f / N_NODES) - m * m;
        float s = gamma[n] * rsqrtf(var + 1e-5f);
        sc[t] = s;
        sh[t] = beta[n] - m * s;
    }
    __syncthreads();
    int r = t >> 5;
    int p0 = (t & 31) * 4;
    int n0 = (p0 & 64) + ((p0 >> 2) & 15);
    for (int row0 = blockIdx.x * 8; row0 < N_NODES; row0 += gridDim.x * 8) {
        int row = row0 + r;
        float4 v = make_float4(0.f, 0.f, 0.f, 0.f);
        if (row < N_NODES) v = *reinterpret_cast<float4*>(h + (size_t)row * 128 + p0);
        v.x = v.x * sc[p0] + sh[p0];
        v.y = v.y * sc[p0 + 1] + sh[p0 + 1];
        v.z = v.z * sc[p0 + 2] + sh[p0 + 2];
        v.w = v.w * sc[p0 + 3] + sh[p0 + 3];
        tile[r][n0]      = v.x;
        tile[r][n0 + 16] = v.y;
        tile[r][n0 + 32] = v.z;
        tile[r][n0 + 48] = v.w;
        __syncthreads();
        if (row < N_NODES)
            *reinterpret_cast<float4*>(h + (size_t)row * 128 + p0) =
                *reinterpret_cast<float4*>(&tile[r][p0]);
        __syncthreads();
    }
}

extern "C" void kernel_launch(void* const* d_in, const int* in_sizes, int n_in,
                              void* d_out, int out_size, void* d_ws, size_t ws_size,
                              hipStream_t stream) {
    (void)in_sizes; (void)n_in; (void)out_size;
    const float* node_feats = (const float*)d_in[0];
    const int* src    = (const int*)d_in[1];
    const int* dst    = (const int*)d_in[2];
    const int* etype  = (const int*)d_in[3];
    const float* norm = (const float*)d_in[4];
    const float* basis = (const float*)d_in[5];
    const float* comp  = (const float*)d_in[6];
    const float* h_bias = (const float*)d_in[7];
    const float* W_res  = (const float*)d_in[8];
    const float* b_res  = (const float*)d_in[9];
    const float* gamma  = (const float*)d_in[10];
    const float* beta   = (const float*)d_in[11];

    char* ws = (char*)d_ws;
    int* ghist      = (int*)(ws + 0);
    int* cnt        = (int*)(ws + 1024);
    int* ntiles_p   = (int*)(ws + 2048);
    float* colsum   = (float*)(ws + 2560);
    float* colsumsq = (float*)(ws + 3072);
    int* tile_rel   = (int*)(ws + 8192);
    int* tile_start = (int*)(ws + 28672);
    int* tile_len   = (int*)(ws + 49152);
    float* W32      = (float*)(ws + 69632);        // 4259840 -> end 4329472
    unsigned short* Wt      = (unsigned short*)(ws + 4329472);   // 2129920 -> 6459392
    unsigned short* Wrest   = (unsigned short*)(ws + 6459392);   // 32768   -> 6492160
    unsigned short* node_bf = (unsigned short*)(ws + 6492160);   // 5120000 -> 11612160
    int* perm       = (int*)(ws + 11612160);       // 2560000 -> 14172160
    int* inv2       = (int*)(ws + 14172160);       // 2560000 -> 16732160
    float* resid    = (float*)(ws + 16732160);     // 10240000 -> 26972160
    int* gh2        = (int*)(ws + 26972160);       // 16*80000 -> 28252160
    int* cnt2       = (int*)(ws + 28252160);       // 16*80000 -> 29532160
    int* seg2       = (int*)(ws + 29532160);       // 16*80004 -> 30812224
    int* bsum       = (int*)(ws + 30812224);       // 16*320   -> 30817344
    const long BASE_END = 30817344L;               // 16B aligned

    int C = 1;
    while (C < 16 && BASE_END + ((long)E_EDGES / C) * 256L > (long)ws_size) C <<= 1;
    int CH = E_EDGES / C;
    unsigned short* t_buf = (unsigned short*)(ws + BASE_END);
    float* hacc = (float*)d_out;

    hipMemsetAsync(ws, 0, 8192, stream);
    hipMemsetAsync(gh2, 0, (size_t)C * N_NODES * 4, stream);
    hipMemsetAsync(d_out, 0, (size_t)N_NODES * 128 * 4, stream);

    k_basis_gemm<<<dim3(64, 5), 256, 0, stream>>>(comp, basis, W32);
    k_transpose_bf16<<<R_REL * 4, 256, 0, stream>>>(W32, Wt);
    k_transpose_bf16<<<4, 256, 0, stream>>>(W_res, Wrest);
    k_f32_to_bf16<<<2500, 256, 0, stream>>>(node_feats, node_bf, N_NODES * 32);
    k_hist<<<256, 256, 0, stream>>>(etype, ghist);
    k_scan_tiles<<<1, 256, 0, stream>>>(ghist, cnt, ntiles_p, tile_rel, tile_start, tile_len, CH);
    k_scatter<<<(E_EDGES + SCAT_CH - 1) / SCAT_CH, 256, 0, stream>>>(etype, cnt, perm);
    k_hist_dst_all<<<640, 256, 0, stream>>>(perm, dst, CH, gh2);
    k_scanA<<<C * 80, 256, 0, stream>>>(gh2, bsum);
    k_scanB<<<1, 256, 0, stream>>>(bsum, C);
    k_scanC<<<C * 80, 256, 0, stream>>>(gh2, bsum, cnt2, seg2, CH);
    k_scatter_dst_all<<<640, 256, 0, stream>>>(perm, dst, CH, cnt2, inv2);
    k_resid_gemm<<<(N_NODES + 127) / 128, 256, 0, stream>>>(node_bf, Wrest, b_res, resid);

    for (int c = 0; c < C; ++c) {
        int lo = c * CH, hi = lo + CH;
        k_conv_gemm<<<MAX_TILES, 256, 0, stream>>>(tile_rel, tile_start, tile_len, ntiles_p,
                                                   perm, src, norm, node_bf, Wt, inv2,
                                                   t_buf, lo, hi);
        k_reduce<<<(N_NODES + 15) / 16, 256, 0, stream>>>(t_buf, seg2 + (size_t)c * SEGSTRIDE,
                                                          (c > 0) ? 1 : 0, hacc);
    }

    k_combine_stats<<<(N_NODES + 63) / 64, 256, 0, stream>>>(hacc, resid, h_bias, colsum, colsumsq);
    k_bn<<<2500, 256, 0, stream>>>(hacc, colsum, colsumsq, gamma, beta);
}

// Round 5
// 383.326 us; speedup vs baseline: 1.4072x; 1.0121x over previous
//
#include <hip/hip_runtime.h>
#include <hip/hip_bf16.h>

// RGCN layer, MI355X — round 5 (r4 fix: NT builtins need native vector types,
// use ext_vector_type u32x4/u32x2 instead of HIP uint4/uint2 there).
// r3 post-mortem: conv 107us, FETCH 134MB vs ~17MB unique reads -> L2 thrash
// from the scattered t_out write stream + random 4B metadata gathers.
// Fixes: NT stores (t_out) / NT loads (reduce); metadata pre-gathered into
// sort order (srcp/normp/dstp, perm dropped); TM=64 -> 3 blocks/CU;
// reduce fused with bias+relu+residual+BN-stats (C==1 path);
// pre-conv scratch aliased into t_buf span.

#define N_NODES 20000
#define E_EDGES 640000
#define R_REL   65
#define TM      64
#define MAX_TILES 10240
#define SEGSTRIDE 20001

typedef __attribute__((ext_vector_type(8))) short bf16x8;
typedef __attribute__((ext_vector_type(4))) float f32x4;
typedef __attribute__((ext_vector_type(4))) unsigned int u32x4;
typedef __attribute__((ext_vector_type(2))) unsigned int u32x2;

__device__ __forceinline__ unsigned short f2bf(float x) {
    union { float f; unsigned int u; } c; c.f = x;
    unsigned int b = c.u + 0x7fffu + ((c.u >> 16) & 1u);   // RTNE
    return (unsigned short)(b >> 16);
}
__device__ __forceinline__ float bf2f_lo(unsigned int u) {
    union { unsigned int u; float f; } c; c.u = u << 16; return c.f;
}
__device__ __forceinline__ float bf2f_hi(unsigned int u) {
    union { unsigned int u; float f; } c; c.u = u & 0xffff0000u; return c.f;
}
__device__ __forceinline__ void async16(const void* g, void* l) {
    __builtin_amdgcn_global_load_lds(
        (const __attribute__((address_space(1))) unsigned int*)g,
        (__attribute__((address_space(3))) unsigned int*)l, 16, 0, 0);
}
// permuted pos -> true col
__device__ __forceinline__ int unperm(int p) {
    return (p & 64) + ((p & 3) << 4) + ((p >> 2) & 15);
}

// ---------------- K0a: W32[r, i*128+o] = sum_b comp[r,b]*basis[b,i,o] ------
__global__ void k_basis_gemm(const float* __restrict__ comp,
                             const float* __restrict__ basis,
                             float* __restrict__ W32) {
    __shared__ float lc[16 * 65];
    int r0 = blockIdx.y * 16;
    int col = blockIdx.x * 256 + threadIdx.x;
    for (int j = threadIdx.x; j < 16 * 65; j += 256) {
        int rr = r0 + j / 65;
        lc[j] = (rr < R_REL) ? comp[rr * 65 + (j % 65)] : 0.f;
    }
    __syncthreads();
    float acc[16];
#pragma unroll
    for (int j = 0; j < 16; ++j) acc[j] = 0.f;
    for (int k = 0; k < 65; ++k) {
        float v = basis[k * 16384 + col];
#pragma unroll
        for (int j = 0; j < 16; ++j) acc[j] += lc[j * 65 + k] * v;
    }
#pragma unroll
    for (int j = 0; j < 16; ++j) {
        int rr = r0 + j;
        if (rr < R_REL) W32[rr * 16384 + col] = acc[j];
    }
}

// ---------------- K0b: transpose fp32 [i][o] -> bf16 [o][i] ----------------
__global__ void k_transpose_bf16(const float* __restrict__ src,
                                 unsigned short* __restrict__ dst) {
    __shared__ float tile[64][65];
    int b = blockIdx.x;
    int mat = b >> 2, ot = (b >> 1) & 1, itl = b & 1;
    const float* s = src + (size_t)mat * 16384;
    unsigned short* d = dst + (size_t)mat * 16384;
    int tx = threadIdx.x & 63, ty = threadIdx.x >> 6;
    for (int it = 0; it < 16; ++it) {
        int i = ty + it * 4;
        tile[i][tx] = s[(itl * 64 + i) * 128 + ot * 64 + tx];
    }
    __syncthreads();
    for (int it = 0; it < 16; ++it) {
        int o = ty + it * 4;
        d[(ot * 64 + o) * 128 + itl * 64 + tx] = f2bf(tile[tx][o]);
    }
}

// ---------------- K0c: node feats fp32 -> bf16 -----------------------------
__global__ void k_f32_to_bf16(const float* __restrict__ x,
                              unsigned short* __restrict__ y, int n4) {
    int i = blockIdx.x * 256 + threadIdx.x;
    if (i >= n4) return;
    float4 v = reinterpret_cast<const float4*>(x)[i];
    ushort4 o;
    o.x = f2bf(v.x); o.y = f2bf(v.y); o.z = f2bf(v.z); o.w = f2bf(v.w);
    reinterpret_cast<ushort4*>(y)[i] = o;
}

// ---------------- K1a: relation histogram ----------------------------------
__global__ void k_hist(const int* __restrict__ et, int* __restrict__ ghist) {
    __shared__ int lh[R_REL];
    if (threadIdx.x < R_REL) lh[threadIdx.x] = 0;
    __syncthreads();
    for (int i = blockIdx.x * 256 + threadIdx.x; i < E_EDGES; i += gridDim.x * 256)
        atomicAdd(&lh[et[i]], 1);
    __syncthreads();
    if (threadIdx.x < R_REL) atomicAdd(&ghist[threadIdx.x], lh[threadIdx.x]);
}

// ---------------- K1b: scan + tile descriptors (split at chunk bounds) -----
__global__ void k_scan_tiles(const int* __restrict__ ghist, int* __restrict__ cnt,
                             int* __restrict__ ntiles_p, int* __restrict__ tile_rel,
                             int* __restrict__ tile_start, int* __restrict__ tile_len,
                             int CH) {
    __shared__ int base[R_REL + 1], tb[R_REL + 1], tcnt[R_REL];
    int tid = threadIdx.x;
    if (tid == 0) {
        int b = 0;
        for (int r = 0; r < R_REL; ++r) {
            base[r] = b; b += ghist[r];
            cnt[r] = base[r];
        }
        base[R_REL] = b;
    }
    __syncthreads();
    if (tid < R_REL) {
        int s = base[tid], e = base[tid + 1], c = 0;
        while (s < e) {
            int tochunk = CH - (s - (s / CH) * CH);
            int len = min(min(TM, e - s), tochunk);
            s += len; ++c;
        }
        tcnt[tid] = c;
    }
    __syncthreads();
    if (tid == 0) {
        int t = 0;
        for (int r = 0; r < R_REL; ++r) { tb[r] = t; t += tcnt[r]; }
        tb[R_REL] = t;
        *ntiles_p = t;
    }
    __syncthreads();
    if (tid < R_REL) {
        int s = base[tid], e = base[tid + 1], j = tb[tid];
        while (s < e) {
            int tochunk = CH - (s - (s / CH) * CH);
            int len = min(min(TM, e - s), tochunk);
            tile_rel[j] = tid; tile_start[j] = s; tile_len[j] = len;
            ++j; s += len;
        }
    }
}

// ---------------- K1c: scatter + metadata pre-gather into sort order -------
#define SCAT_CH 2560
__global__ void k_scatter(const int* __restrict__ et, const int* __restrict__ srcA,
                          const int* __restrict__ dstA, const float* __restrict__ norm,
                          int* __restrict__ cnt, int* __restrict__ srcp,
                          float* __restrict__ normp, int* __restrict__ dstp) {
    __shared__ int lh[R_REL], lbase[R_REL];
    int c0 = blockIdx.x * SCAT_CH;
    int cend = min(c0 + SCAT_CH, E_EDGES);
    if (threadIdx.x < R_REL) lh[threadIdx.x] = 0;
    __syncthreads();
    for (int i = c0 + threadIdx.x; i < cend; i += 256) atomicAdd(&lh[et[i]], 1);
    __syncthreads();
    if (threadIdx.x < R_REL && lh[threadIdx.x] > 0)
        lbase[threadIdx.x] = atomicAdd(&cnt[threadIdx.x], lh[threadIdx.x]);
    __syncthreads();
    if (threadIdx.x < R_REL) lh[threadIdx.x] = 0;
    __syncthreads();
    for (int i = c0 + threadIdx.x; i < cend; i += 256) {
        int r = et[i];
        int p = lbase[r] + atomicAdd(&lh[r], 1);
        srcp[p] = srcA[i];
        dstp[p] = dstA[i];
        normp[p] = norm[i];
    }
}

// ---------------- K1d: dst histogram, all chunks (sequential dstp) ---------
__global__ void k_hist_dst_all(const int* __restrict__ dstp, int CH,
                               int* __restrict__ gh2) {
    for (int i = blockIdx.x * 256 + threadIdx.x; i < E_EDGES; i += gridDim.x * 256) {
        int c = i / CH;
        atomicAdd(&gh2[c * N_NODES + dstp[i]], 1);
    }
}

// ---------------- K1e: 3-phase parallel scan per chunk ---------------------
__global__ void k_scanA(const int* __restrict__ gh2, int* __restrict__ bsum) {
    int c = blockIdx.x / 80, jb = blockIdx.x % 80;
    int i = jb * 256 + threadIdx.x;
    int v = (i < N_NODES) ? gh2[c * N_NODES + i] : 0;
    __shared__ int red[256];
    red[threadIdx.x] = v;
    __syncthreads();
    for (int off = 128; off > 0; off >>= 1) {
        if (threadIdx.x < off) red[threadIdx.x] += red[threadIdx.x + off];
        __syncthreads();
    }
    if (threadIdx.x == 0) bsum[c * 80 + jb] = red[0];
}

__global__ void k_scanB(int* __restrict__ bsum, int nchunks) {
    int w = threadIdx.x >> 6, l = threadIdx.x & 63;
    for (int c = w; c < nchunks; c += 4) {
        int* b = bsum + c * 80;
        int v0 = b[l];
        int x = v0;
#pragma unroll
        for (int off = 1; off < 64; off <<= 1) {
            int y = __shfl_up(x, off);
            if (l >= off) x += y;
        }
        int tot0 = __shfl(x, 63);
        int v1 = (l < 16) ? b[64 + l] : 0;
        int x1 = v1;
#pragma unroll
        for (int off = 1; off < 16; off <<= 1) {
            int y = __shfl_up(x1, off);
            if (l >= off) x1 += y;
        }
        b[l] = x - v0;                       // exclusive
        if (l < 16) b[64 + l] = (x1 - v1) + tot0;
    }
}

__global__ void k_scanC(const int* __restrict__ gh2, const int* __restrict__ bsum,
                        int* __restrict__ cnt2, int* __restrict__ seg2, int CH) {
    int c = blockIdx.x / 80, jb = blockIdx.x % 80;
    int i = jb * 256 + threadIdx.x;
    int v = (i < N_NODES) ? gh2[c * N_NODES + i] : 0;
    __shared__ int red[256];
    red[threadIdx.x] = v;
    __syncthreads();
    for (int off = 1; off < 256; off <<= 1) {
        int x = (threadIdx.x >= off) ? red[threadIdx.x - off] : 0;
        __syncthreads();
        red[threadIdx.x] += x;
        __syncthreads();
    }
    int excl = red[threadIdx.x] - v + bsum[c * 80 + jb];
    if (i < N_NODES) {
        cnt2[c * N_NODES + i] = excl;
        seg2[c * SEGSTRIDE + i] = excl;
        if (i == N_NODES - 1) seg2[c * SEGSTRIDE + N_NODES] = excl + v;   // == CH
    }
}

// ---------------- K1f: scatter -> inv2 (position within chunk) -------------
__global__ void k_scatter_dst_all(const int* __restrict__ dstp, int CH,
                                  int* __restrict__ cnt2, int* __restrict__ inv2) {
    for (int i = blockIdx.x * 256 + threadIdx.x; i < E_EDGES; i += gridDim.x * 256) {
        int c = i / CH;
        inv2[i] = atomicAdd(&cnt2[c * N_NODES + dstp[i]], 1);
    }
}

// ---------------- K2: per-relation edge GEMM -> bf16 rows at dst-pos -------
// TM=64: A 16KB + B 32KB + meta -> 3 blocks/CU.
__global__ __launch_bounds__(256, 3) void k_conv_gemm(
    const int* __restrict__ tile_rel, const int* __restrict__ tile_start,
    const int* __restrict__ tile_len, const int* __restrict__ ntiles_p,
    const int* __restrict__ srcp, const float* __restrict__ normp,
    const unsigned short* __restrict__ node_bf,
    const unsigned short* __restrict__ Wt, const int* __restrict__ inv2,
    unsigned short* __restrict__ t_out, int lo, int hi) {
    __shared__ unsigned short Alds[64 * 128];
    __shared__ unsigned short Blds[128 * 128];
    __shared__ float snorm[64];
    __shared__ int sp2[64];
    int tid = blockIdx.x;
    if (tid >= *ntiles_p) return;
    int start = tile_start[tid];
    if (start < lo || start >= hi) return;
    int r = tile_rel[tid], len = tile_len[tid];
    int t = threadIdx.x;
    const unsigned short* Wr = Wt + (size_t)r * 16384;
#pragma unroll
    for (int it = 0; it < 8; ++it) {               // stage W: XOR on SOURCE chunk
        int j = t + 256 * it;
        int o = j >> 4, c = j & 15, cs = c ^ (o & 15);
        async16(Wr + o * 128 + cs * 8, &Blds[o * 128 + c * 8]);
    }
#pragma unroll
    for (int it = 0; it < 4; ++it) {               // stage A: sequential metadata
        int j = t + 256 * it;
        int p = j >> 4, c = j & 15, cs = c ^ (p & 15);
        if (p < len) {
            int s = srcp[start + p];
            async16(node_bf + (size_t)s * 128 + cs * 8, &Alds[p * 128 + c * 8]);
        }
    }
    if (t < TM && t < len) {
        snorm[t] = normp[start + t];
        sp2[t] = inv2[start + t];
    }
    __syncthreads();

    int w = t >> 6, lane = t & 63;
    int wr = (w >> 1) * 32, wc = (w & 1) * 64;
    int lrow = lane & 15, quad = lane >> 4;
    f32x4 acc[2][4];
#pragma unroll
    for (int i = 0; i < 2; ++i)
#pragma unroll
        for (int j = 0; j < 4; ++j) acc[i][j] = (f32x4){0.f, 0.f, 0.f, 0.f};

#pragma unroll
    for (int ks = 0; ks < 4; ++ks) {
        int cbase = ks * 4 + quad;
        bf16x8 af[2], bfr[4];
#pragma unroll
        for (int i = 0; i < 2; ++i) {
            int row = wr + i * 16 + lrow;
            int cs = cbase ^ (row & 15);
            af[i] = *reinterpret_cast<const bf16x8*>(&Alds[row * 128 + cs * 8]);
        }
#pragma unroll
        for (int j = 0; j < 4; ++j) {
            int row = wc + j * 16 + lrow;
            int cs = cbase ^ (row & 15);
            bfr[j] = *reinterpret_cast<const bf16x8*>(&Blds[row * 128 + cs * 8]);
        }
#pragma unroll
        for (int i = 0; i < 2; ++i)
#pragma unroll
            for (int j = 0; j < 4; ++j)
                acc[i][j] = __builtin_amdgcn_mfma_f32_16x16x32_bf16(af[i], bfr[j], acc[i][j], 0, 0, 0);
    }

    // epilogue: scale by norm, pack bf16, NT-store permuted row chunk.
#pragma unroll
    for (int i = 0; i < 2; ++i) {
        int m0 = wr + i * 16 + quad * 4;
#pragma unroll
        for (int reg = 0; reg < 4; ++reg) {
            int m = m0 + reg;
            if (m < len) {
                float nm = snorm[m];
                int p2 = sp2[m];
                float2 lo2 = make_float2(acc[i][0][reg] * nm, acc[i][1][reg] * nm);
                float2 hi2 = make_float2(acc[i][2][reg] * nm, acc[i][3][reg] * nm);
                __hip_bfloat162 blo = __float22bfloat162_rn(lo2);
                __hip_bfloat162 bhi = __float22bfloat162_rn(hi2);
                u32x2 st;
                st.x = *reinterpret_cast<unsigned int*>(&blo);
                st.y = *reinterpret_cast<unsigned int*>(&bhi);
                __builtin_nontemporal_store(st,
                    reinterpret_cast<u32x2*>(t_out + (size_t)p2 * 128 + wc + lrow * 4));
            }
        }
    }
}

// ---------------- K2b: fused CSR reduce + bias/relu/resid + BN stats (C==1)
__global__ __launch_bounds__(256) void k_reduce_fused(
    const unsigned short* __restrict__ t, const int* __restrict__ seg,
    const float* __restrict__ resid, const float* __restrict__ h_bias,
    float* __restrict__ h, float* __restrict__ colsum, float* __restrict__ colsumsq) {
    __shared__ float cs1[128], cs2[128];
    if (threadIdx.x < 128) { cs1[threadIdx.x] = 0.f; cs2[threadIdx.x] = 0.f; }
    __syncthreads();
    int d = blockIdx.x * 16 + (threadIdx.x >> 4);
    int c = threadIdx.x & 15;
    int a = seg[d], b = seg[d + 1];
    float s[8];
#pragma unroll
    for (int k = 0; k < 8; ++k) s[k] = 0.f;
    int q = a;
    for (; q + 4 <= b; q += 4) {
        u32x4 v0 = __builtin_nontemporal_load(reinterpret_cast<const u32x4*>(t + (size_t)(q + 0) * 128 + c * 8));
        u32x4 v1 = __builtin_nontemporal_load(reinterpret_cast<const u32x4*>(t + (size_t)(q + 1) * 128 + c * 8));
        u32x4 v2 = __builtin_nontemporal_load(reinterpret_cast<const u32x4*>(t + (size_t)(q + 2) * 128 + c * 8));
        u32x4 v3 = __builtin_nontemporal_load(reinterpret_cast<const u32x4*>(t + (size_t)(q + 3) * 128 + c * 8));
        const u32x4 vs[4] = {v0, v1, v2, v3};
#pragma unroll
        for (int z = 0; z < 4; ++z) {
#pragma unroll
            for (int k = 0; k < 4; ++k) {
                s[2 * k]     += bf2f_lo(vs[z][k]);
                s[2 * k + 1] += bf2f_hi(vs[z][k]);
            }
        }
    }
    for (; q < b; ++q) {
        u32x4 v = __builtin_nontemporal_load(reinterpret_cast<const u32x4*>(t + (size_t)q * 128 + c * 8));
#pragma unroll
        for (int k = 0; k < 4; ++k) {
            s[2 * k]     += bf2f_lo(v[k]);
            s[2 * k + 1] += bf2f_hi(v[k]);
        }
    }
    const float* rp = resid + (size_t)d * 128 + c * 8;
    float4 r0 = *reinterpret_cast<const float4*>(rp);
    float4 r1 = *reinterpret_cast<const float4*>(rp + 4);
    float rr[8] = {r0.x, r0.y, r0.z, r0.w, r1.x, r1.y, r1.z, r1.w};
    float v[8];
#pragma unroll
    for (int k = 0; k < 8; ++k) {
        int p = c * 8 + k;
        float bias = h_bias[unperm(p)];
        v[k] = fmaxf(s[k] + bias, 0.f) + rr[k];
    }
    float* hp = h + (size_t)d * 128 + c * 8;
    *reinterpret_cast<float4*>(hp)     = make_float4(v[0], v[1], v[2], v[3]);
    *reinterpret_cast<float4*>(hp + 4) = make_float4(v[4], v[5], v[6], v[7]);
#pragma unroll
    for (int k = 0; k < 8; ++k) {
        atomicAdd(&cs1[c * 8 + k], v[k]);
        atomicAdd(&cs2[c * 8 + k], v[k] * v[k]);
    }
    __syncthreads();
    if (threadIdx.x < 128) {
        atomicAdd(&colsum[threadIdx.x], cs1[threadIdx.x]);
        atomicAdd(&colsumsq[threadIdx.x], cs2[threadIdx.x]);
    }
}

// ---------------- K2c: plain CSR reduce (C>1 fallback) ---------------------
__global__ __launch_bounds__(256) void k_reduce(const unsigned short* __restrict__ t,
                                                const int* __restrict__ seg,
                                                int accum, float* __restrict__ h) {
    int d = blockIdx.x * 16 + (threadIdx.x >> 4);
    if (d >= N_NODES) return;
    int c = threadIdx.x & 15;
    int a = seg[d], b = seg[d + 1];
    if (a == b) return;
    float s[8];
#pragma unroll
    for (int k = 0; k < 8; ++k) s[k] = 0.f;
    int q = a;
    for (; q + 4 <= b; q += 4) {
        u32x4 v0 = __builtin_nontemporal_load(reinterpret_cast<const u32x4*>(t + (size_t)(q + 0) * 128 + c * 8));
        u32x4 v1 = __builtin_nontemporal_load(reinterpret_cast<const u32x4*>(t + (size_t)(q + 1) * 128 + c * 8));
        u32x4 v2 = __builtin_nontemporal_load(reinterpret_cast<const u32x4*>(t + (size_t)(q + 2) * 128 + c * 8));
        u32x4 v3 = __builtin_nontemporal_load(reinterpret_cast<const u32x4*>(t + (size_t)(q + 3) * 128 + c * 8));
        const u32x4 vs[4] = {v0, v1, v2, v3};
#pragma unroll
        for (int z = 0; z < 4; ++z) {
#pragma unroll
            for (int k = 0; k < 4; ++k) {
                s[2 * k]     += bf2f_lo(vs[z][k]);
                s[2 * k + 1] += bf2f_hi(vs[z][k]);
            }
        }
    }
    for (; q < b; ++q) {
        u32x4 v = __builtin_nontemporal_load(reinterpret_cast<const u32x4*>(t + (size_t)q * 128 + c * 8));
#pragma unroll
        for (int k = 0; k < 4; ++k) {
            s[2 * k]     += bf2f_lo(v[k]);
            s[2 * k + 1] += bf2f_hi(v[k]);
        }
    }
    float* p = h + (size_t)d * 128 + c * 8;
    if (accum) {
        float4 e0 = *reinterpret_cast<float4*>(p);
        float4 e1 = *reinterpret_cast<float4*>(p + 4);
        s[0] += e0.x; s[1] += e0.y; s[2] += e0.z; s[3] += e0.w;
        s[4] += e1.x; s[5] += e1.y; s[6] += e1.z; s[7] += e1.w;
    }
    *reinterpret_cast<float4*>(p)     = make_float4(s[0], s[1], s[2], s[3]);
    *reinterpret_cast<float4*>(p + 4) = make_float4(s[4], s[5], s[6], s[7]);
}

// ---------------- K3: residual GEMM relu(x @ W_res + b_res), permuted store
__global__ __launch_bounds__(256, 2) void k_resid_gemm(
    const unsigned short* __restrict__ node_bf,
    const unsigned short* __restrict__ Wrest, const float* __restrict__ b_res,
    float* __restrict__ resid) {
    __shared__ unsigned short Alds[128 * 128];
    __shared__ unsigned short Blds[128 * 128];
    int row0 = blockIdx.x * 128;
    int t = threadIdx.x;
    int nrows = min(128, N_NODES - row0);
#pragma unroll
    for (int it = 0; it < 8; ++it) {
        int j = t + 256 * it;
        int o = j >> 4, c = j & 15, cs = c ^ (o & 15);
        async16(Wrest + o * 128 + cs * 8, &Blds[o * 128 + c * 8]);
    }
#pragma unroll
    for (int it = 0; it < 8; ++it) {
        int j = t + 256 * it;
        int p = j >> 4, c = j & 15, cs = c ^ (p & 15);
        if (p < nrows)
            async16(node_bf + (size_t)(row0 + p) * 128 + cs * 8, &Alds[p * 128 + c * 8]);
    }
    __syncthreads();

    int w = t >> 6, lane = t & 63;
    int wr = (w >> 1) * 64, wc = (w & 1) * 64;
    int lrow = lane & 15, quad = lane >> 4;
    f32x4 acc[4][4];
#pragma unroll
    for (int i = 0; i < 4; ++i)
#pragma unroll
        for (int j = 0; j < 4; ++j) acc[i][j] = (f32x4){0.f, 0.f, 0.f, 0.f};
#pragma unroll
    for (int ks = 0; ks < 4; ++ks) {
        int cbase = ks * 4 + quad;
        bf16x8 af[4], bfr[4];
#pragma unroll
        for (int i = 0; i < 4; ++i) {
            int row = wr + i * 16 + lrow;
            int cs = cbase ^ (row & 15);
            af[i] = *reinterpret_cast<const bf16x8*>(&Alds[row * 128 + cs * 8]);
        }
#pragma unroll
        for (int j = 0; j < 4; ++j) {
            int row = wc + j * 16 + lrow;
            int cs = cbase ^ (row & 15);
            bfr[j] = *reinterpret_cast<const bf16x8*>(&Blds[row * 128 + cs * 8]);
        }
#pragma unroll
        for (int i = 0; i < 4; ++i)
#pragma unroll
            for (int j = 0; j < 4; ++j)
                acc[i][j] = __builtin_amdgcn_mfma_f32_16x16x32_bf16(af[i], bfr[j], acc[i][j], 0, 0, 0);
    }
    float br0 = b_res[wc + lrow];
    float br1 = b_res[wc + 16 + lrow];
    float br2 = b_res[wc + 32 + lrow];
    float br3 = b_res[wc + 48 + lrow];
#pragma unroll
    for (int i = 0; i < 4; ++i) {
        int m0 = wr + i * 16 + quad * 4;
#pragma unroll
        for (int reg = 0; reg < 4; ++reg) {
            int grow = row0 + m0 + reg;
            if (grow < N_NODES) {
                float4 v;
                v.x = fmaxf(acc[i][0][reg] + br0, 0.f);
                v.y = fmaxf(acc[i][1][reg] + br1, 0.f);
                v.z = fmaxf(acc[i][2][reg] + br2, 0.f);
                v.w = fmaxf(acc[i][3][reg] + br3, 0.f);
                *reinterpret_cast<float4*>(resid + (size_t)grow * 128 + wc + lrow * 4) = v;
            }
        }
    }
}

// ---------------- K4: combine (C>1 fallback) -------------------------------
__global__ void k_combine_stats(float* __restrict__ h, const float* __restrict__ resid,
                                const float* __restrict__ h_bias,
                                float* __restrict__ colsum, float* __restrict__ colsumsq) {
    int p = threadIdx.x & 127, half = threadIdx.x >> 7;
    int row0 = blockIdx.x * 64;
    float bias = h_bias[unperm(p)];
    float s1 = 0.f, s2 = 0.f;
    for (int it = 0; it < 32; ++it) {
        int row = row0 + half * 32 + it;
        if (row < N_NODES) {
            size_t idx = (size_t)row * 128 + p;
            float v = fmaxf(h[idx] + bias, 0.f) + resid[idx];
            h[idx] = v;
            s1 += v; s2 += v * v;
        }
    }
    __shared__ float ls1[256], ls2[256];
    ls1[threadIdx.x] = s1; ls2[threadIdx.x] = s2;
    __syncthreads();
    if (threadIdx.x < 128) {
        atomicAdd(&colsum[threadIdx.x], ls1[threadIdx.x] + ls1[threadIdx.x + 128]);
        atomicAdd(&colsumsq[threadIdx.x], ls2[threadIdx.x] + ls2[threadIdx.x + 128]);
    }
}

// ---------------- K5: BN apply + unpermute to natural cols -----------------
__global__ void k_bn(float* __restrict__ h, const float* __restrict__ colsum,
                     const float* __restrict__ colsumsq, const float* __restrict__ gamma,
                     const float* __restrict__ beta) {
    __shared__ float sc[128], sh[128], tile[8][128];
    int t = threadIdx.x;
    if (t < 128) {
        int n = unperm(t);
        float m = colsum[t] * (1.f / N_NODES);
        float var = colsumsq[t] * (1.f / N_NODES) - m * m;
        float s = gamma[n] * rsqrtf(var + 1e-5f);
        sc[t] = s;
        sh[t] = beta[n] - m * s;
    }
    __syncthreads();
    int r = t >> 5;
    int p0 = (t & 31) * 4;
    int n0 = (p0 & 64) + ((p0 >> 2) & 15);
    for (int row0 = blockIdx.x * 8; row0 < N_NODES; row0 += gridDim.x * 8) {
        int row = row0 + r;
        float4 v = make_float4(0.f, 0.f, 0.f, 0.f);
        if (row < N_NODES) v = *reinterpret_cast<float4*>(h + (size_t)row * 128 + p0);
        v.x = v.x * sc[p0] + sh[p0];
        v.y = v.y * sc[p0 + 1] + sh[p0 + 1];
        v.z = v.z * sc[p0 + 2] + sh[p0 + 2];
        v.w = v.w * sc[p0 + 3] + sh[p0 + 3];
        tile[r][n0]      = v.x;
        tile[r][n0 + 16] = v.y;
        tile[r][n0 + 32] = v.z;
        tile[r][n0 + 48] = v.w;
        __syncthreads();
        if (row < N_NODES)
            *reinterpret_cast<float4*>(h + (size_t)row * 128 + p0) =
                *reinterpret_cast<float4*>(&tile[r][p0]);
        __syncthreads();
    }
}

extern "C" void kernel_launch(void* const* d_in, const int* in_sizes, int n_in,
                              void* d_out, int out_size, void* d_ws, size_t ws_size,
                              hipStream_t stream) {
    (void)in_sizes; (void)n_in; (void)out_size;
    const float* node_feats = (const float*)d_in[0];
    const int* src    = (const int*)d_in[1];
    const int* dst    = (const int*)d_in[2];
    const int* etype  = (const int*)d_in[3];
    const float* norm = (const float*)d_in[4];
    const float* basis = (const float*)d_in[5];
    const float* comp  = (const float*)d_in[6];
    const float* h_bias = (const float*)d_in[7];
    const float* W_res  = (const float*)d_in[8];
    const float* b_res  = (const float*)d_in[9];
    const float* gamma  = (const float*)d_in[10];
    const float* beta   = (const float*)d_in[11];

    char* ws = (char*)d_ws;
    int* ghist      = (int*)(ws + 0);
    int* cnt        = (int*)(ws + 1024);
    int* ntiles_p   = (int*)(ws + 2048);
    float* colsum   = (float*)(ws + 2560);
    float* colsumsq = (float*)(ws + 3072);
    int* tile_rel   = (int*)(ws + 8192);       // 40960
    int* tile_start = (int*)(ws + 49152);      // 40960
    int* tile_len   = (int*)(ws + 90112);      // 40960 -> 131072
    unsigned short* Wt      = (unsigned short*)(ws + 131072);    // 2129920 -> 2260992
    unsigned short* Wrest   = (unsigned short*)(ws + 2260992);   // 32768   -> 2293760
    unsigned short* node_bf = (unsigned short*)(ws + 2293760);   // 5120000 -> 7413760
    int* srcp       = (int*)(ws + 7413760);    // 2560000 -> 9973760
    float* normp    = (float*)(ws + 9973760);  // 2560000 -> 12533760
    int* inv2       = (int*)(ws + 12533760);   // 2560000 -> 15093760
    float* resid    = (float*)(ws + 15093760); // 10240000 -> 25333760
    int* seg2       = (int*)(ws + 25333760);   // 16*80004 -> 26613824
    const long BASE_END = 26613824L;           // 16B aligned

    // pre-conv scratch aliased into the t_buf span (dead before conv writes)
    float* W32      = (float*)(ws + BASE_END);               // 4259840
    int* gh2        = (int*)(ws + BASE_END + 4259840);       // 1280000
    int* cnt2       = (int*)(ws + BASE_END + 5539840);       // 1280000
    int* bsum       = (int*)(ws + BASE_END + 6819840);       // 5120 -> 6824960
    int* dstp       = (int*)(ws + BASE_END + 6824960);       // 2560000 -> 9384960

    int C = 1;
    while (C < 16 && BASE_END + ((long)E_EDGES / C) * 256L > (long)ws_size) C <<= 1;
    int CH = E_EDGES / C;
    unsigned short* t_buf = (unsigned short*)(ws + BASE_END);
    float* hacc = (float*)d_out;

    hipMemsetAsync(ws, 0, 8192, stream);
    hipMemsetAsync(gh2, 0, (size_t)C * N_NODES * 4, stream);

    k_basis_gemm<<<dim3(64, 5), 256, 0, stream>>>(comp, basis, W32);
    k_transpose_bf16<<<R_REL * 4, 256, 0, stream>>>(W32, Wt);
    k_transpose_bf16<<<4, 256, 0, stream>>>(W_res, Wrest);
    k_f32_to_bf16<<<2500, 256, 0, stream>>>(node_feats, node_bf, N_NODES * 32);
    k_hist<<<256, 256, 0, stream>>>(etype, ghist);
    k_scan_tiles<<<1, 256, 0, stream>>>(ghist, cnt, ntiles_p, tile_rel, tile_start, tile_len, CH);
    k_scatter<<<(E_EDGES + SCAT_CH - 1) / SCAT_CH, 256, 0, stream>>>(
        etype, src, dst, norm, cnt, srcp, normp, dstp);
    k_hist_dst_all<<<640, 256, 0, stream>>>(dstp, CH, gh2);
    k_scanA<<<C * 80, 256, 0, stream>>>(gh2, bsum);
    k_scanB<<<1, 256, 0, stream>>>(bsum, C);
    k_scanC<<<C * 80, 256, 0, stream>>>(gh2, bsum, cnt2, seg2, CH);
    k_scatter_dst_all<<<640, 256, 0, stream>>>(dstp, CH, cnt2, inv2);
    k_resid_gemm<<<(N_NODES + 127) / 128, 256, 0, stream>>>(node_bf, Wrest, b_res, resid);

    if (C == 1) {
        k_conv_gemm<<<MAX_TILES, 256, 0, stream>>>(tile_rel, tile_start, tile_len, ntiles_p,
                                                   srcp, normp, node_bf, Wt, inv2,
                                                   t_buf, 0, E_EDGES);
        k_reduce_fused<<<N_NODES / 16, 256, 0, stream>>>(t_buf, seg2, resid, h_bias,
                                                         hacc, colsum, colsumsq);
    } else {
        hipMemsetAsync(d_out, 0, (size_t)N_NODES * 128 * 4, stream);
        for (int c = 0; c < C; ++c) {
            int lo = c * CH, hi = lo + CH;
            k_conv_gemm<<<MAX_TILES, 256, 0, stream>>>(tile_rel, tile_start, tile_len, ntiles_p,
                                                       srcp, normp, node_bf, Wt, inv2,
                                                       t_buf, lo, hi);
            k_reduce<<<(N_NODES + 15) / 16, 256, 0, stream>>>(t_buf, seg2 + (size_t)c * SEGSTRIDE,
                                                              (c > 0) ? 1 : 0, hacc);
        }
        k_combine_stats<<<(N_NODES + 63) / 64, 256, 0, stream>>>(hacc, resid, h_bias,
                                                                 colsum, colsumsq);
    }
    k_bn<<<2500, 256, 0, stream>>>(hacc, colsum, colsumsq, gamma, beta);
}

// Round 6
// 367.798 us; speedup vs baseline: 1.4667x; 1.0422x over previous
//
#include <hip/hip_runtime.h>
#include <hip/hip_bf16.h>

// RGCN layer, MI355X — round 6.
// r5 post-mortem: conv 82us ok, but ~300us is the tail (reduce ~75us + 18
// serialized dispatches + serial scan_tiles). C==1 confirmed (conv WRITE =
// full 164MB t_buf) -> chunked fallback dropped.
// This round: super-tiles (W staged once per 256 edges, B-frags hoisted to
// regs), pipeline fused 18->14 dispatches (merged hists, inv2 in scatter,
// cvt in resid, parallel scans), reduce = wave-per-dst w/ shfl_xor.

#define N_NODES 20000
#define E_EDGES 640000
#define R_REL   65
#define STM     256          // super-tile edges
#define MAX_TILES 2600
#define SCAT_CH 2560

typedef __attribute__((ext_vector_type(8))) short bf16x8;
typedef __attribute__((ext_vector_type(4))) float f32x4;
typedef __attribute__((ext_vector_type(4))) unsigned int u32x4;
typedef __attribute__((ext_vector_type(2))) unsigned int u32x2;

__device__ __forceinline__ unsigned short f2bf(float x) {
    union { float f; unsigned int u; } c; c.f = x;
    unsigned int b = c.u + 0x7fffu + ((c.u >> 16) & 1u);   // RTNE
    return (unsigned short)(b >> 16);
}
__device__ __forceinline__ float bf2f_lo(unsigned int u) {
    union { unsigned int u; float f; } c; c.u = u << 16; return c.f;
}
__device__ __forceinline__ float bf2f_hi(unsigned int u) {
    union { unsigned int u; float f; } c; c.u = u & 0xffff0000u; return c.f;
}
__device__ __forceinline__ void async16(const void* g, void* l) {
    __builtin_amdgcn_global_load_lds(
        (const __attribute__((address_space(1))) unsigned int*)g,
        (__attribute__((address_space(3))) unsigned int*)l, 16, 0, 0);
}
__device__ __forceinline__ int unperm(int p) {      // permuted pos -> true col
    return (p & 64) + ((p & 3) << 4) + ((p >> 2) & 15);
}

// ---------------- K0a: W32[r, i*128+o] = sum_b comp[r,b]*basis[b,i,o] ------
__global__ void k_basis_gemm(const float* __restrict__ comp,
                             const float* __restrict__ basis,
                             float* __restrict__ W32) {
    __shared__ float lc[16 * 65];
    int r0 = blockIdx.y * 16;
    int col = blockIdx.x * 256 + threadIdx.x;
    for (int j = threadIdx.x; j < 16 * 65; j += 256) {
        int rr = r0 + j / 65;
        lc[j] = (rr < R_REL) ? comp[rr * 65 + (j % 65)] : 0.f;
    }
    __syncthreads();
    float acc[16];
#pragma unroll
    for (int j = 0; j < 16; ++j) acc[j] = 0.f;
    for (int k = 0; k < 65; ++k) {
        float v = basis[k * 16384 + col];
#pragma unroll
        for (int j = 0; j < 16; ++j) acc[j] += lc[j * 65 + k] * v;
    }
#pragma unroll
    for (int j = 0; j < 16; ++j) {
        int rr = r0 + j;
        if (rr < R_REL) W32[rr * 16384 + col] = acc[j];
    }
}

// ---------------- K0b: transpose fp32 [i][o] -> bf16 [o][i] ----------------
__global__ void k_transpose_bf16(const float* __restrict__ src,
                                 unsigned short* __restrict__ dst) {
    __shared__ float tile[64][65];
    int b = blockIdx.x;
    int mat = b >> 2, ot = (b >> 1) & 1, itl = b & 1;
    const float* s = src + (size_t)mat * 16384;
    unsigned short* d = dst + (size_t)mat * 16384;
    int tx = threadIdx.x & 63, ty = threadIdx.x >> 6;
    for (int it = 0; it < 16; ++it) {
        int i = ty + it * 4;
        tile[i][tx] = s[(itl * 64 + i) * 128 + ot * 64 + tx];
    }
    __syncthreads();
    for (int it = 0; it < 16; ++it) {
        int o = ty + it * 4;
        d[(ot * 64 + o) * 128 + itl * 64 + tx] = f2bf(tile[tx][o]);
    }
}

// ---------------- K1a: etype histogram + dst histogram, one pass -----------
__global__ void k_hist2(const int* __restrict__ et, const int* __restrict__ dstA,
                        int* __restrict__ ghist, int* __restrict__ gh2) {
    __shared__ int lh[R_REL];
    if (threadIdx.x < R_REL) lh[threadIdx.x] = 0;
    __syncthreads();
    for (int i = blockIdx.x * 256 + threadIdx.x; i < E_EDGES; i += gridDim.x * 256) {
        atomicAdd(&lh[et[i]], 1);
        atomicAdd(&gh2[dstA[i]], 1);
    }
    __syncthreads();
    if (threadIdx.x < R_REL) atomicAdd(&ghist[threadIdx.x], lh[threadIdx.x]);
}

// ---------------- K1b: per-block partial sums of gh2 -----------------------
__global__ void k_scanA(const int* __restrict__ gh2, int* __restrict__ bsum) {
    int i = blockIdx.x * 256 + threadIdx.x;
    int v = (i < N_NODES) ? gh2[i] : 0;
    __shared__ int red[256];
    red[threadIdx.x] = v;
    __syncthreads();
    for (int off = 128; off > 0; off >>= 1) {
        if (threadIdx.x < off) red[threadIdx.x] += red[threadIdx.x + off];
        __syncthreads();
    }
    if (threadIdx.x == 0) bsum[blockIdx.x] = red[0];
}

// ---------------- K1c: small scans: bsum[80], ghist->base, tile descs ------
__global__ void k_scan_small(const int* __restrict__ ghist, int* __restrict__ bsum,
                             int* __restrict__ cnt, int* __restrict__ ntiles_p,
                             int* __restrict__ tile_rel, int* __restrict__ tile_start,
                             int* __restrict__ tile_len) {
    __shared__ int base[R_REL + 1], tbase[R_REL + 1];
    int t = threadIdx.x, w = t >> 6, lane = t & 63;
    if (w == 0) {                                   // exclusive scan bsum[80]
        int v0 = bsum[lane];
        int x = v0;
#pragma unroll
        for (int off = 1; off < 64; off <<= 1) {
            int y = __shfl_up(x, off);
            if (lane >= off) x += y;
        }
        int tot0 = __shfl(x, 63);
        int v1 = (lane < 16) ? bsum[64 + lane] : 0;
        int x1 = v1;
#pragma unroll
        for (int off = 1; off < 16; off <<= 1) {
            int y = __shfl_up(x1, off);
            if (lane >= off) x1 += y;
        }
        bsum[lane] = x - v0;
        if (lane < 16) bsum[64 + lane] = (x1 - v1) + tot0;
    } else if (w == 1) {                            // exclusive scan ghist[65]
        int v = (lane < 64) ? ghist[lane] : 0;
        int x = v;
#pragma unroll
        for (int off = 1; off < 64; off <<= 1) {
            int y = __shfl_up(x, off);
            if (lane >= off) x += y;
        }
        base[lane] = x - v;
        if (lane == 63) {
            base[64] = x;
            base[65] = x + ghist[64];
        }
    }
    __syncthreads();
    if (t == 0) {
        int tb = 0;
        for (int r = 0; r < R_REL; ++r) {
            tbase[r] = tb;
            int h = base[r + 1] - base[r];
            tb += (h + STM - 1) / STM;
        }
        *ntiles_p = tb;
    }
    __syncthreads();
    if (t < R_REL) {
        cnt[t] = base[t];
        int s = base[t], e = base[t + 1], j = tbase[t];
        while (s < e) {
            int len = min(STM, e - s);
            tile_rel[j] = t; tile_start[j] = s; tile_len[j] = len;
            ++j; s += len;
        }
    }
}

// ---------------- K1d: block scan -> cnt2 (dst bases) + seg ----------------
__global__ void k_scanC(const int* __restrict__ gh2, const int* __restrict__ bsum,
                        int* __restrict__ cnt2, int* __restrict__ seg) {
    int i = blockIdx.x * 256 + threadIdx.x;
    int v = (i < N_NODES) ? gh2[i] : 0;
    __shared__ int red[256];
    red[threadIdx.x] = v;
    __syncthreads();
    for (int off = 1; off < 256; off <<= 1) {
        int x = (threadIdx.x >= off) ? red[threadIdx.x - off] : 0;
        __syncthreads();
        red[threadIdx.x] += x;
        __syncthreads();
    }
    int excl = red[threadIdx.x] - v + bsum[blockIdx.x];
    if (i < N_NODES) {
        cnt2[i] = excl;
        seg[i] = excl;
        if (i == N_NODES - 1) seg[N_NODES] = excl + v;   // == E
    }
}

// ---------------- K1e: rel scatter + dst-position assignment ---------------
__global__ void k_scatter2(const int* __restrict__ et, const int* __restrict__ srcA,
                           const int* __restrict__ dstA, const float* __restrict__ norm,
                           int* __restrict__ cnt, int* __restrict__ cnt2,
                           int* __restrict__ srcp, float* __restrict__ normp,
                           int* __restrict__ inv2) {
    __shared__ int lh[R_REL], lbase[R_REL];
    int c0 = blockIdx.x * SCAT_CH;
    int cend = min(c0 + SCAT_CH, E_EDGES);
    if (threadIdx.x < R_REL) lh[threadIdx.x] = 0;
    __syncthreads();
    for (int i = c0 + threadIdx.x; i < cend; i += 256) atomicAdd(&lh[et[i]], 1);
    __syncthreads();
    if (threadIdx.x < R_REL && lh[threadIdx.x] > 0)
        lbase[threadIdx.x] = atomicAdd(&cnt[threadIdx.x], lh[threadIdx.x]);
    __syncthreads();
    if (threadIdx.x < R_REL) lh[threadIdx.x] = 0;
    __syncthreads();
    for (int i = c0 + threadIdx.x; i < cend; i += 256) {
        int r = et[i];
        int p = lbase[r] + atomicAdd(&lh[r], 1);
        srcp[p] = srcA[i];
        normp[p] = norm[i];
        inv2[p] = atomicAdd(&cnt2[dstA[i]], 1);
    }
}

// ---------------- K2: super-tile edge GEMM -> bf16 rows at dst-pos ---------
// W staged once per 256 edges; 4 sub-tiles of 64; B-frags hoisted to regs.
// LDS: B 32K + A 16K + meta 2K = 50K -> 3 blocks/CU.
__global__ __launch_bounds__(256, 3) void k_conv_gemm(
    const int* __restrict__ tile_rel, const int* __restrict__ tile_start,
    const int* __restrict__ tile_len, const int* __restrict__ ntiles_p,
    const int* __restrict__ srcp, const float* __restrict__ normp,
    const unsigned short* __restrict__ node_bf,
    const unsigned short* __restrict__ Wt, const int* __restrict__ inv2,
    unsigned short* __restrict__ t_out) {
    __shared__ unsigned short Blds[128 * 128];
    __shared__ unsigned short Alds[64 * 128];
    __shared__ float snorm[STM];
    __shared__ int sp2[STM];
    int tid = blockIdx.x;
    if (tid >= *ntiles_p) return;
    int r = tile_rel[tid], start = tile_start[tid], len = tile_len[tid];
    int t = threadIdx.x;
    const unsigned short* Wr = Wt + (size_t)r * 16384;
#pragma unroll
    for (int it = 0; it < 8; ++it) {               // stage W (XOR on source)
        int j = t + 256 * it;
        int o = j >> 4, c = j & 15, cs = c ^ (o & 15);
        async16(Wr + o * 128 + cs * 8, &Blds[o * 128 + c * 8]);
    }
    if (t < len) {
        snorm[t] = normp[start + t];
        sp2[t] = inv2[start + t];
    }
#pragma unroll
    for (int it = 0; it < 4; ++it) {               // stage A sub-tile 0
        int j = t + 256 * it;
        int p = j >> 4, c = j & 15, cs = c ^ (p & 15);
        if (p < len)
            async16(node_bf + (size_t)srcp[start + p] * 128 + cs * 8,
                    &Alds[p * 128 + c * 8]);
    }
    int nsub = (len + 63) >> 6;
    int w = t >> 6, lane = t & 63;
    int wr = (w >> 1) * 32, wc = (w & 1) * 64;
    int lrow = lane & 15, quad = lane >> 4;

    __syncthreads();                               // W + A0 + meta ready
    bf16x8 ball[4][4];                             // hoisted B frags
#pragma unroll
    for (int ks = 0; ks < 4; ++ks) {
        int cbase = ks * 4 + quad;
#pragma unroll
        for (int j = 0; j < 4; ++j) {
            int row = wc + j * 16 + lrow;
            int cs = cbase ^ (row & 15);
            ball[ks][j] = *reinterpret_cast<const bf16x8*>(&Blds[row * 128 + cs * 8]);
        }
    }
    for (int s = 0; s < nsub; ++s) {
        if (s > 0) __syncthreads();                // A(s) staged
        f32x4 acc[2][4];
#pragma unroll
        for (int i = 0; i < 2; ++i)
#pragma unroll
            for (int j = 0; j < 4; ++j) acc[i][j] = (f32x4){0.f, 0.f, 0.f, 0.f};
#pragma unroll
        for (int ks = 0; ks < 4; ++ks) {
            int cbase = ks * 4 + quad;
            bf16x8 af[2];
#pragma unroll
            for (int i = 0; i < 2; ++i) {
                int row = wr + i * 16 + lrow;
                int cs = cbase ^ (row & 15);
                af[i] = *reinterpret_cast<const bf16x8*>(&Alds[row * 128 + cs * 8]);
            }
#pragma unroll
            for (int i = 0; i < 2; ++i)
#pragma unroll
                for (int j = 0; j < 4; ++j)
                    acc[i][j] = __builtin_amdgcn_mfma_f32_16x16x32_bf16(af[i], ball[ks][j], acc[i][j], 0, 0, 0);
        }
        __syncthreads();                           // all waves done with Alds
        int nb = (s + 1) * 64;
        if (nb < len) {                            // stage A(s+1) (overlaps epilogue)
#pragma unroll
            for (int it = 0; it < 4; ++it) {
                int j = t + 256 * it;
                int p = j >> 4, c = j & 15, cs = c ^ (p & 15);
                int gp = nb + p;
                if (gp < len)
                    async16(node_bf + (size_t)srcp[start + gp] * 128 + cs * 8,
                            &Alds[p * 128 + c * 8]);
            }
        }
        int sbase = s * 64;                        // epilogue for s
#pragma unroll
        for (int i = 0; i < 2; ++i) {
            int m0 = sbase + wr + i * 16 + quad * 4;
#pragma unroll
            for (int reg = 0; reg < 4; ++reg) {
                int m = m0 + reg;
                if (m < len) {
                    float nm = snorm[m];
                    int p2 = sp2[m];
                    float2 lo2 = make_float2(acc[i][0][reg] * nm, acc[i][1][reg] * nm);
                    float2 hi2 = make_float2(acc[i][2][reg] * nm, acc[i][3][reg] * nm);
                    __hip_bfloat162 blo = __float22bfloat162_rn(lo2);
                    __hip_bfloat162 bhi = __float22bfloat162_rn(hi2);
                    u32x2 st;
                    st.x = *reinterpret_cast<unsigned int*>(&blo);
                    st.y = *reinterpret_cast<unsigned int*>(&bhi);
                    __builtin_nontemporal_store(st,
                        reinterpret_cast<u32x2*>(t_out + (size_t)p2 * 128 + wc + lrow * 4));
                }
            }
        }
    }
}

// ---------------- K2b: wave-per-dst CSR reduce + bias/relu/resid + stats ---
__global__ __launch_bounds__(256) void k_reduce_fused(
    const unsigned short* __restrict__ t, const int* __restrict__ seg,
    const float* __restrict__ resid, const float* __restrict__ h_bias,
    float* __restrict__ h, float* __restrict__ colsum, float* __restrict__ colsumsq) {
    __shared__ float cs1[128], cs2[128], sbias[128];
    if (threadIdx.x < 128) {
        cs1[threadIdx.x] = 0.f; cs2[threadIdx.x] = 0.f;
        sbias[threadIdx.x] = h_bias[unperm(threadIdx.x)];
    }
    __syncthreads();
    int w = threadIdx.x >> 6, lane = threadIdx.x & 63;
    int g = lane >> 4, c = lane & 15;
    for (int k = 0; k < 4; ++k) {
        int d = blockIdx.x * 16 + k * 4 + w;
        int a = seg[d], b = seg[d + 1];
        float s[8];
#pragma unroll
        for (int kk = 0; kk < 8; ++kk) s[kk] = 0.f;
        int q = a + g;
        for (; q + 4 < b; q += 8) {
            u32x4 v0 = __builtin_nontemporal_load(reinterpret_cast<const u32x4*>(t + (size_t)q * 128 + c * 8));
            u32x4 v1 = __builtin_nontemporal_load(reinterpret_cast<const u32x4*>(t + (size_t)(q + 4) * 128 + c * 8));
#pragma unroll
            for (int kk = 0; kk < 4; ++kk) {
                s[2 * kk]     += bf2f_lo(v0[kk]) + bf2f_lo(v1[kk]);
                s[2 * kk + 1] += bf2f_hi(v0[kk]) + bf2f_hi(v1[kk]);
            }
        }
        for (; q < b; q += 4) {
            u32x4 v = __builtin_nontemporal_load(reinterpret_cast<const u32x4*>(t + (size_t)q * 128 + c * 8));
#pragma unroll
            for (int kk = 0; kk < 4; ++kk) {
                s[2 * kk]     += bf2f_lo(v[kk]);
                s[2 * kk + 1] += bf2f_hi(v[kk]);
            }
        }
#pragma unroll
        for (int kk = 0; kk < 8; ++kk) {           // cross-row-group reduce
            s[kk] += __shfl_xor(s[kk], 16);
            s[kk] += __shfl_xor(s[kk], 32);
        }
        if (g == 0) {
            const float* rp = resid + (size_t)d * 128 + c * 8;
            float4 r0 = *reinterpret_cast<const float4*>(rp);
            float4 r1 = *reinterpret_cast<const float4*>(rp + 4);
            float rr[8] = {r0.x, r0.y, r0.z, r0.w, r1.x, r1.y, r1.z, r1.w};
            float v[8];
#pragma unroll
            for (int kk = 0; kk < 8; ++kk)
                v[kk] = fmaxf(s[kk] + sbias[c * 8 + kk], 0.f) + rr[kk];
            float* hp = h + (size_t)d * 128 + c * 8;
            *reinterpret_cast<float4*>(hp)     = make_float4(v[0], v[1], v[2], v[3]);
            *reinterpret_cast<float4*>(hp + 4) = make_float4(v[4], v[5], v[6], v[7]);
#pragma unroll
            for (int kk = 0; kk < 8; ++kk) {
                atomicAdd(&cs1[c * 8 + kk], v[kk]);
                atomicAdd(&cs2[c * 8 + kk], v[kk] * v[kk]);
            }
        }
    }
    __syncthreads();
    if (threadIdx.x < 128) {
        atomicAdd(&colsum[threadIdx.x], cs1[threadIdx.x]);
        atomicAdd(&colsumsq[threadIdx.x], cs2[threadIdx.x]);
    }
}

// ---------------- K3: residual GEMM + fused fp32->bf16 conversion ----------
__global__ __launch_bounds__(256, 2) void k_resid_gemm(
    const float* __restrict__ node_feats, unsigned short* __restrict__ node_bf,
    const unsigned short* __restrict__ Wrest, const float* __restrict__ b_res,
    float* __restrict__ resid) {
    __shared__ unsigned short Alds[128 * 128];
    __shared__ unsigned short Blds[128 * 128];
    int row0 = blockIdx.x * 128;
    int t = threadIdx.x;
    int nrows = min(128, N_NODES - row0);
#pragma unroll
    for (int it = 0; it < 8; ++it) {
        int j = t + 256 * it;
        int o = j >> 4, c = j & 15, cs = c ^ (o & 15);
        async16(Wrest + o * 128 + cs * 8, &Blds[o * 128 + c * 8]);
    }
#pragma unroll
    for (int it = 0; it < 8; ++it) {               // load fp32, cvt, stage + emit
        int j = t + 256 * it;
        int p = j >> 4, cg = j & 15;
        if (p < nrows) {
            const float* sp = node_feats + (size_t)(row0 + p) * 128 + cg * 8;
            float4 f0 = *reinterpret_cast<const float4*>(sp);
            float4 f1 = *reinterpret_cast<const float4*>(sp + 4);
            __hip_bfloat162 b0 = __float22bfloat162_rn(make_float2(f0.x, f0.y));
            __hip_bfloat162 b1 = __float22bfloat162_rn(make_float2(f0.z, f0.w));
            __hip_bfloat162 b2 = __float22bfloat162_rn(make_float2(f1.x, f1.y));
            __hip_bfloat162 b3 = __float22bfloat162_rn(make_float2(f1.z, f1.w));
            u32x4 pk;
            pk.x = *reinterpret_cast<unsigned int*>(&b0);
            pk.y = *reinterpret_cast<unsigned int*>(&b1);
            pk.z = *reinterpret_cast<unsigned int*>(&b2);
            pk.w = *reinterpret_cast<unsigned int*>(&b3);
            int cl = cg ^ (p & 15);
            *reinterpret_cast<u32x4*>(&Alds[p * 128 + cl * 8]) = pk;
            *reinterpret_cast<u32x4*>(node_bf + (size_t)(row0 + p) * 128 + cg * 8) = pk;
        }
    }
    __syncthreads();

    int w = t >> 6, lane = t & 63;
    int wr = (w >> 1) * 64, wc = (w & 1) * 64;
    int lrow = lane & 15, quad = lane >> 4;
    f32x4 acc[4][4];
#pragma unroll
    for (int i = 0; i < 4; ++i)
#pragma unroll
        for (int j = 0; j < 4; ++j) acc[i][j] = (f32x4){0.f, 0.f, 0.f, 0.f};
#pragma unroll
    for (int ks = 0; ks < 4; ++ks) {
        int cbase = ks * 4 + quad;
        bf16x8 af[4], bfr[4];
#pragma unroll
        for (int i = 0; i < 4; ++i) {
            int row = wr + i * 16 + lrow;
            int cs = cbase ^ (row & 15);
            af[i] = *reinterpret_cast<const bf16x8*>(&Alds[row * 128 + cs * 8]);
        }
#pragma unroll
        for (int j = 0; j < 4; ++j) {
            int row = wc + j * 16 + lrow;
            int cs = cbase ^ (row & 15);
            bfr[j] = *reinterpret_cast<const bf16x8*>(&Blds[row * 128 + cs * 8]);
        }
#pragma unroll
        for (int i = 0; i < 4; ++i)
#pragma unroll
            for (int j = 0; j < 4; ++j)
                acc[i][j] = __builtin_amdgcn_mfma_f32_16x16x32_bf16(af[i], bfr[j], acc[i][j], 0, 0, 0);
    }
    float br0 = b_res[wc + lrow];
    float br1 = b_res[wc + 16 + lrow];
    float br2 = b_res[wc + 32 + lrow];
    float br3 = b_res[wc + 48 + lrow];
#pragma unroll
    for (int i = 0; i < 4; ++i) {
        int m0 = wr + i * 16 + quad * 4;
#pragma unroll
        for (int reg = 0; reg < 4; ++reg) {
            int grow = row0 + m0 + reg;
            if (grow < N_NODES) {
                float4 v;
                v.x = fmaxf(acc[i][0][reg] + br0, 0.f);
                v.y = fmaxf(acc[i][1][reg] + br1, 0.f);
                v.z = fmaxf(acc[i][2][reg] + br2, 0.f);
                v.w = fmaxf(acc[i][3][reg] + br3, 0.f);
                *reinterpret_cast<float4*>(resid + (size_t)grow * 128 + wc + lrow * 4) = v;
            }
        }
    }
}

// ---------------- K5: BN apply + unpermute to natural cols -----------------
__global__ void k_bn(float* __restrict__ h, const float* __restrict__ colsum,
                     const float* __restrict__ colsumsq, const float* __restrict__ gamma,
                     const float* __restrict__ beta) {
    __shared__ float sc[128], sh[128], tile[8][128];
    int t = threadIdx.x;
    if (t < 128) {
        int n = unperm(t);
        float m = colsum[t] * (1.f / N_NODES);
        float var = colsumsq[t] * (1.f / N_NODES) - m * m;
        float s = gamma[n] * rsqrtf(var + 1e-5f);
        sc[t] = s;
        sh[t] = beta[n] - m * s;
    }
    __syncthreads();
    int r = t >> 5;
    int p0 = (t & 31) * 4;
    int n0 = (p0 & 64) + ((p0 >> 2) & 15);
    for (int row0 = blockIdx.x * 8; row0 < N_NODES; row0 += gridDim.x * 8) {
        int row = row0 + r;
        float4 v = make_float4(0.f, 0.f, 0.f, 0.f);
        if (row < N_NODES) v = *reinterpret_cast<float4*>(h + (size_t)row * 128 + p0);
        v.x = v.x * sc[p0] + sh[p0];
        v.y = v.y * sc[p0 + 1] + sh[p0 + 1];
        v.z = v.z * sc[p0 + 2] + sh[p0 + 2];
        v.w = v.w * sc[p0 + 3] + sh[p0 + 3];
        tile[r][n0]      = v.x;
        tile[r][n0 + 16] = v.y;
        tile[r][n0 + 32] = v.z;
        tile[r][n0 + 48] = v.w;
        __syncthreads();
        if (row < N_NODES)
            *reinterpret_cast<float4*>(h + (size_t)row * 128 + p0) =
                *reinterpret_cast<float4*>(&tile[r][p0]);
        __syncthreads();
    }
}

extern "C" void kernel_launch(void* const* d_in, const int* in_sizes, int n_in,
                              void* d_out, int out_size, void* d_ws, size_t ws_size,
                              hipStream_t stream) {
    (void)in_sizes; (void)n_in; (void)out_size; (void)ws_size;
    const float* node_feats = (const float*)d_in[0];
    const int* src    = (const int*)d_in[1];
    const int* dst    = (const int*)d_in[2];
    const int* etype  = (const int*)d_in[3];
    const float* norm = (const float*)d_in[4];
    const float* basis = (const float*)d_in[5];
    const float* comp  = (const float*)d_in[6];
    const float* h_bias = (const float*)d_in[7];
    const float* W_res  = (const float*)d_in[8];
    const float* b_res  = (const float*)d_in[9];
    const float* gamma  = (const float*)d_in[10];
    const float* beta   = (const float*)d_in[11];

    char* ws = (char*)d_ws;
    int* ghist      = (int*)(ws + 0);
    int* cnt        = (int*)(ws + 1024);
    int* ntiles_p   = (int*)(ws + 2048);
    float* colsum   = (float*)(ws + 2560);
    float* colsumsq = (float*)(ws + 3072);
    int* tile_rel   = (int*)(ws + 8192);
    int* tile_start = (int*)(ws + 24576);
    int* tile_len   = (int*)(ws + 40960);                        // end 57344
    unsigned short* Wt      = (unsigned short*)(ws + 57344);     // 2129920 -> 2187264
    unsigned short* Wrest   = (unsigned short*)(ws + 2187264);   // 32768   -> 2220032
    unsigned short* node_bf = (unsigned short*)(ws + 2220032);   // 5120000 -> 7340032
    int* srcp       = (int*)(ws + 7340032);    // 2560000 -> 9900032
    float* normp    = (float*)(ws + 9900032);  // 2560000 -> 12460032
    int* inv2       = (int*)(ws + 12460032);   // 2560000 -> 15020032
    float* resid    = (float*)(ws + 15020032); // 10240000 -> 25260032
    int* seg        = (int*)(ws + 25260032);   // 80004 -> 25340036, pad
    int* gh2        = (int*)(ws + 25340048);   // 80000 -> 25420048
    int* cnt2       = (int*)(ws + 25420048);   // 80000 -> 25500048
    int* bsum       = (int*)(ws + 25500048);   // 320   -> 25500368
    const long T_BASE = 25500368L;             // 16B aligned
    float* W32      = (float*)(ws + T_BASE);   // aliased: dead before conv
    unsigned short* t_buf = (unsigned short*)(ws + T_BASE);      // 163.84 MB
    float* hacc = (float*)d_out;

    hipMemsetAsync(ws, 0, 8192, stream);
    hipMemsetAsync(gh2, 0, N_NODES * 4, stream);

    k_basis_gemm<<<dim3(64, 5), 256, 0, stream>>>(comp, basis, W32);
    k_transpose_bf16<<<R_REL * 4, 256, 0, stream>>>(W32, Wt);
    k_transpose_bf16<<<4, 256, 0, stream>>>(W_res, Wrest);
    k_hist2<<<512, 256, 0, stream>>>(etype, dst, ghist, gh2);
    k_scanA<<<80, 256, 0, stream>>>(gh2, bsum);
    k_scan_small<<<1, 256, 0, stream>>>(ghist, bsum, cnt, ntiles_p,
                                        tile_rel, tile_start, tile_len);
    k_scanC<<<80, 256, 0, stream>>>(gh2, bsum, cnt2, seg);
    k_scatter2<<<(E_EDGES + SCAT_CH - 1) / SCAT_CH, 256, 0, stream>>>(
        etype, src, dst, norm, cnt, cnt2, srcp, normp, inv2);
    k_resid_gemm<<<(N_NODES + 127) / 128, 256, 0, stream>>>(
        node_feats, node_bf, Wrest, b_res, resid);
    k_conv_gemm<<<MAX_TILES, 256, 0, stream>>>(tile_rel, tile_start, tile_len, ntiles_p,
                                               srcp, normp, node_bf, Wt, inv2, t_buf);
    k_reduce_fused<<<N_NODES / 16, 256, 0, stream>>>(t_buf, seg, resid, h_bias,
                                                     hacc, colsum, colsumsq);
    k_bn<<<2500, 256, 0, stream>>>(hacc, colsum, colsumsq, gamma, beta);
}